// Round 1
// baseline (201.513 us; speedup 1.0000x reference)
//
#include <hip/hip_runtime.h>
#include <cmath>

#define BB 2
#define LL 256
#define DD 512
#define HH 8
#define DHH 64

__device__ __forceinline__ float4 ld4(const float* p) { return *reinterpret_cast<const float4*>(p); }
__device__ __forceinline__ void st4(float* p, float4 v) { *reinterpret_cast<float4*>(p) = v; }
__device__ __forceinline__ void fma4(float4& a, float s, const float4& v) {
    a.x = fmaf(s, v.x, a.x); a.y = fmaf(s, v.y, a.y);
    a.z = fmaf(s, v.z, a.z); a.w = fmaf(s, v.w, a.w);
}
__device__ __forceinline__ float dot4(const float4& a, const float4& b) {
    return a.x*b.x + a.y*b.y + a.z*b.z + a.w*b.w;
}

// ---------------- K0: transpose Wq,Wk,Wv,Wf -> Wt[k][n] ----------------
__global__ __launch_bounds__(256) void k_transpose(
        const float* __restrict__ Wq, const float* __restrict__ Wk,
        const float* __restrict__ Wv, const float* __restrict__ Wf,
        float* __restrict__ Wt) {
    __shared__ float tile[32][33];
    int mat = blockIdx.z;
    const float* W = (mat == 0) ? Wq : (mat == 1) ? Wk : (mat == 2) ? Wv : Wf;
    float* out = Wt + mat * 512 * 512;
    int n0 = blockIdx.x * 32, k0 = blockIdx.y * 32;
    int tx = threadIdx.x & 31, ty = threadIdx.x >> 5;  // ty 0..7
#pragma unroll
    for (int r = 0; r < 4; r++) {
        int row = ty * 4 + r;
        tile[row][tx] = W[(n0 + row) * 512 + k0 + tx];
    }
    __syncthreads();
#pragma unroll
    for (int r = 0; r < 4; r++) {
        int row = ty * 4 + r;
        out[(k0 + row) * 512 + n0 + tx] = tile[tx][row];
    }
}

// ---------------- K1: q/k/v projections ----------------
// C[m,n] = x[m,:] . W[n,:] + b[n]; scatter to [B,H,L,DH]
// grid (2 n-halves, 64 m-tiles, 3 mats), block 256
__global__ __launch_bounds__(256) void k_qkv(
        const float* __restrict__ x, const float* __restrict__ Wt,
        const float* __restrict__ bq, const float* __restrict__ bk, const float* __restrict__ bv,
        float* __restrict__ qw, float* __restrict__ kw, float* __restrict__ vw) {
    int mat = blockIdx.z;
    const float* WT = Wt + mat * 512 * 512;
    const float* bias = (mat == 0) ? bq : (mat == 1) ? bk : bv;
    float* out = (mat == 0) ? qw : (mat == 1) ? kw : vw;
    int n0 = blockIdx.x * 256, m0 = blockIdx.y * 8;
    __shared__ float As[8][512];
    int t = threadIdx.x;
    {
        const float4* src = reinterpret_cast<const float4*>(x + m0 * 512);
        float4* dst = reinterpret_cast<float4*>(&As[0][0]);
#pragma unroll
        for (int r = 0; r < 4; r++) dst[t + r * 256] = src[t + r * 256];
    }
    __syncthreads();
    int n = n0 + (t & 63) * 4;
    int mg = t >> 6;
    int r0 = mg * 2, r1 = r0 + 1;
    float4 acc0 = {0, 0, 0, 0}, acc1 = {0, 0, 0, 0};
    for (int k4 = 0; k4 < 512; k4 += 4) {
        float4 a0 = ld4(&As[r0][k4]);
        float4 a1 = ld4(&As[r1][k4]);
        float4 w0 = ld4(&WT[(k4 + 0) * 512 + n]);
        float4 w1 = ld4(&WT[(k4 + 1) * 512 + n]);
        float4 w2 = ld4(&WT[(k4 + 2) * 512 + n]);
        float4 w3 = ld4(&WT[(k4 + 3) * 512 + n]);
        fma4(acc0, a0.x, w0); fma4(acc0, a0.y, w1); fma4(acc0, a0.z, w2); fma4(acc0, a0.w, w3);
        fma4(acc1, a1.x, w0); fma4(acc1, a1.y, w1); fma4(acc1, a1.z, w2); fma4(acc1, a1.w, w3);
    }
    float4 b4 = ld4(&bias[n]);
    int h = n >> 6, d = n & 63;
    {
        int m = m0 + r0; int b = m >> 8, i = m & 255;
        float4 o; o.x = acc0.x + b4.x; o.y = acc0.y + b4.y; o.z = acc0.z + b4.z; o.w = acc0.w + b4.w;
        st4(out + (((b * 8 + h) * 256 + i) * 64 + d), o);
    }
    {
        int m = m0 + r1; int b = m >> 8, i = m & 255;
        float4 o; o.x = acc1.x + b4.x; o.y = acc1.y + b4.y; o.z = acc1.z + b4.z; o.w = acc1.w + b4.w;
        st4(out + (((b * 8 + h) * 256 + i) * 64 + d), o);
    }
}

// ---------------- K2: w[b,h,i,e] = (q+v)[b,h,i,:] . Wr[h*64:,:], c = (q+v).br ----------------
// grid (64 m-tiles, 8 h), block 256
__global__ __launch_bounds__(256) void k_wgemm(
        const float* __restrict__ qw, const float* __restrict__ vbias,
        const float* __restrict__ Wr, const float* __restrict__ br,
        float* __restrict__ w_ws, float* __restrict__ c_ws) {
    int m0 = blockIdx.x * 8, h = blockIdx.y;
    __shared__ float qv[8][64];
    int t = threadIdx.x;
    {
        int idx = t * 2;
        int r = idx >> 6, d = idx & 63;
        int m = m0 + r; int b = m >> 8, i = m & 255;
        const float* qrow = qw + ((b * 8 + h) * 256 + i) * 64;
        qv[r][d] = qrow[d] + vbias[h * 64 + d];
        qv[r][d + 1] = qrow[d + 1] + vbias[h * 64 + d + 1];
    }
    __syncthreads();
    if (t < 8) {
        float c = 0.f;
        for (int d = 0; d < 64; d++) c += qv[t][d] * br[h * 64 + d];
        int m = m0 + t; int b = m >> 8, i = m & 255;
        c_ws[(b * 8 + h) * 256 + i] = c;
    }
    int el = (t & 127) * 4;
    int mg = t >> 7;  // 0..1, 4 rows each
    float4 acc[4] = {{0,0,0,0},{0,0,0,0},{0,0,0,0},{0,0,0,0}};
    for (int d = 0; d < 64; d++) {
        float4 wr4 = ld4(&Wr[(h * 64 + d) * 512 + el]);
#pragma unroll
        for (int r = 0; r < 4; r++) fma4(acc[r], qv[mg * 4 + r][d], wr4);
    }
#pragma unroll
    for (int r = 0; r < 4; r++) {
        int m = m0 + mg * 4 + r; int b = m >> 8, i = m & 255;
        st4(&w_ws[((b * 256 + i) * 8 + h) * 512 + el], acc[r]);
    }
}

// ---------------- K3: AC'[b,h,i,j] = (q+u)_i . k_j + c[b,h,i] ----------------
// grid (16 i-tiles, 8 h, 2 b), block 256
__global__ __launch_bounds__(256) void k_ac(
        const float* __restrict__ qw, const float* __restrict__ kw,
        const float* __restrict__ u, const float* __restrict__ c_ws,
        float* __restrict__ ac_ws) {
    int i0 = blockIdx.x * 16, h = blockIdx.y, b = blockIdx.z;
    __shared__ float qu[16][64];
    int t = threadIdx.x;
    {
        int idx = t * 4; int r = idx >> 6, d = idx & 63;
        const float* qrow = qw + ((b * 8 + h) * 256 + i0 + r) * 64;
        float4 q4 = ld4(&qrow[d]);
        float4 u4 = ld4(&u[h * 64 + d]);
        float4 o; o.x = q4.x + u4.x; o.y = q4.y + u4.y; o.z = q4.z + u4.z; o.w = q4.w + u4.w;
        st4(&qu[r][d], o);
    }
    __syncthreads();
    int jg = t & 31, ig = t >> 5;  // ig 0..7 (2 rows each)
    float acc0[8] = {0,0,0,0,0,0,0,0};
    float acc1[8] = {0,0,0,0,0,0,0,0};
    const float* kbase = kw + (b * 8 + h) * 256 * 64;
    for (int d4 = 0; d4 < 64; d4 += 4) {
        float4 q0 = ld4(&qu[ig * 2 + 0][d4]);
        float4 q1 = ld4(&qu[ig * 2 + 1][d4]);
#pragma unroll
        for (int r = 0; r < 8; r++) {
            int j = jg + r * 32;
            float4 k4 = ld4(&kbase[j * 64 + d4]);
            acc0[r] += dot4(q0, k4);
            acc1[r] += dot4(q1, k4);
        }
    }
    int i_0 = i0 + ig * 2, i_1 = i_0 + 1;
    float c0 = c_ws[(b * 8 + h) * 256 + i_0];
    float c1 = c_ws[(b * 8 + h) * 256 + i_1];
#pragma unroll
    for (int r = 0; r < 8; r++) {
        int j = jg + r * 32;
        ac_ws[((b * 256 + i_0) * 8 + h) * 256 + j] = acc0[r] + c0;
        ac_ws[((b * 256 + i_1) * 8 + h) * 256 + j] = acc1[r] + c1;
    }
}

// ---------------- K4: fused B_D + score + softmax + PV ----------------
// grid 512 = (b,i), block 512 = 8 waves
__global__ __launch_bounds__(512) void k_attn(
        const float* __restrict__ pos, const float* __restrict__ w_ws,
        const float* __restrict__ ac_ws, const float* __restrict__ vw,
        const int* __restrict__ seq_mask, float* __restrict__ ctx) {
    int bi = blockIdx.x;
    int b = bi >> 8, i = bi & 255;
    int t = threadIdx.x;
    int wv = t >> 6, lane = t & 63;
    __shared__ float sc[8][256];            // scores -> attn
    __shared__ float4 part[8][4][16];       // PV partials

    // per-lane e-slice of w for all 8 heads: 64 VGPRs
    float4 wr[8][2];
    const float* wbase = w_ws + (size_t)(b * 256 + i) * 8 * 512 + lane * 8;
#pragma unroll
    for (int h = 0; h < 8; h++) {
        wr[h][0] = ld4(&wbase[h * 512]);
        wr[h][1] = ld4(&wbase[h * 512 + 4]);
    }

    const float* prow0 = pos + (size_t)bi * 256 * 512 + lane * 8;
    for (int jj = 0; jj < 32; jj++) {
        int j = wv * 32 + jj;
        float4 p0 = ld4(&prow0[(size_t)j * 512]);
        float4 p1 = ld4(&prow0[(size_t)j * 512 + 4]);
        float a[8];
#pragma unroll
        for (int h = 0; h < 8; h++) {
            a[h] = dot4(p0, wr[h][0]) + dot4(p1, wr[h][1]);
        }
#pragma unroll
        for (int h = 0; h < 8; h++) {
#pragma unroll
            for (int m = 32; m >= 1; m >>= 1) a[h] += __shfl_xor(a[h], m, 64);
        }
        if (lane == 0) {
#pragma unroll
            for (int h = 0; h < 8; h++) sc[h][j] = a[h];
        }
    }
    __syncthreads();

    // softmax: wave wv owns head h = wv
    {
        int h = wv;
        const float* acrow = ac_ws + ((b * 256 + i) * 8 + h) * 256;
        float vals[4];
        float mx = -INFINITY;
#pragma unroll
        for (int r = 0; r < 4; r++) {
            int j = lane + r * 64;
            float s = (sc[h][j] + acrow[j]) * 0.125f;
            if (seq_mask[b * 256 + j] == 0) s = -1e15f;
            vals[r] = s;
            mx = fmaxf(mx, s);
        }
#pragma unroll
        for (int m = 32; m >= 1; m >>= 1) mx = fmaxf(mx, __shfl_xor(mx, m, 64));
        float sum = 0.f;
#pragma unroll
        for (int r = 0; r < 4; r++) { vals[r] = __expf(vals[r] - mx); sum += vals[r]; }
#pragma unroll
        for (int m = 32; m >= 1; m >>= 1) sum += __shfl_xor(sum, m, 64);
        float inv = 1.0f / sum;
#pragma unroll
        for (int r = 0; r < 4; r++) sc[h][lane + r * 64] = vals[r] * inv;
    }
    __syncthreads();

    // PV: wave = head; lane -> (jsplit = lane>>4, d4 = (lane&15)*4)
    {
        int h = wv;
        int d4 = (lane & 15) * 4;
        int js = lane >> 4;
        const float* vbase = vw + (size_t)(b * 8 + h) * 256 * 64;
        float4 acc = {0, 0, 0, 0};
        for (int r = 0; r < 64; r++) {
            int j = js * 64 + r;
            float p = sc[h][j];
            float4 v4 = ld4(&vbase[j * 64 + d4]);
            fma4(acc, p, v4);
        }
        part[h][js][lane & 15] = acc;
    }
    __syncthreads();
    {
        int h = wv;
        if ((lane >> 4) == 0) {
            int l = lane & 15;
            float4 a0 = part[h][0][l], a1 = part[h][1][l], a2 = part[h][2][l], a3 = part[h][3][l];
            float4 o;
            o.x = a0.x + a1.x + a2.x + a3.x;
            o.y = a0.y + a1.y + a2.y + a3.y;
            o.z = a0.z + a1.z + a2.z + a3.z;
            o.w = a0.w + a1.w + a2.w + a3.w;
            st4(ctx + (size_t)(b * 256 + i) * 512 + h * 64 + l * 4, o);
        }
    }
}

// ---------------- K5: FFN GEMM + bias + residual ----------------
// grid (2 n-halves, 64 m-tiles), block 256
__global__ __launch_bounds__(256) void k_ffn(
        const float* __restrict__ A, const float* __restrict__ WT,
        const float* __restrict__ bias, const float* __restrict__ resid,
        float* __restrict__ outp) {
    int n0 = blockIdx.x * 256, m0 = blockIdx.y * 8;
    __shared__ float As[8][512];
    int t = threadIdx.x;
    {
        const float4* src = reinterpret_cast<const float4*>(A + m0 * 512);
        float4* dst = reinterpret_cast<float4*>(&As[0][0]);
#pragma unroll
        for (int r = 0; r < 4; r++) dst[t + r * 256] = src[t + r * 256];
    }
    __syncthreads();
    int n = n0 + (t & 63) * 4;
    int mg = t >> 6;
    int r0 = mg * 2, r1 = r0 + 1;
    float4 acc0 = {0, 0, 0, 0}, acc1 = {0, 0, 0, 0};
    for (int k4 = 0; k4 < 512; k4 += 4) {
        float4 a0 = ld4(&As[r0][k4]);
        float4 a1 = ld4(&As[r1][k4]);
        float4 w0 = ld4(&WT[(k4 + 0) * 512 + n]);
        float4 w1 = ld4(&WT[(k4 + 1) * 512 + n]);
        float4 w2 = ld4(&WT[(k4 + 2) * 512 + n]);
        float4 w3 = ld4(&WT[(k4 + 3) * 512 + n]);
        fma4(acc0, a0.x, w0); fma4(acc0, a0.y, w1); fma4(acc0, a0.z, w2); fma4(acc0, a0.w, w3);
        fma4(acc1, a1.x, w0); fma4(acc1, a1.y, w1); fma4(acc1, a1.z, w2); fma4(acc1, a1.w, w3);
    }
    float4 b4 = ld4(&bias[n]);
    {
        int m = m0 + r0;
        float4 res = ld4(&resid[m * 512 + n]);
        float4 o; o.x = acc0.x + b4.x + res.x; o.y = acc0.y + b4.y + res.y;
        o.z = acc0.z + b4.z + res.z; o.w = acc0.w + b4.w + res.w;
        st4(&outp[m * 512 + n], o);
    }
    {
        int m = m0 + r1;
        float4 res = ld4(&resid[m * 512 + n]);
        float4 o; o.x = acc1.x + b4.x + res.x; o.y = acc1.y + b4.y + res.y;
        o.z = acc1.z + b4.z + res.z; o.w = acc1.w + b4.w + res.w;
        st4(&outp[m * 512 + n], o);
    }
}

// ---------------- K6: LayerNorm ----------------
__global__ __launch_bounds__(256) void k_ln(
        const float* __restrict__ tmp, const float* __restrict__ gamma,
        const float* __restrict__ beta, float* __restrict__ out) {
    int m = blockIdx.x, t = threadIdx.x;
    int wv = t >> 6, lane = t & 63;
    float2 xv = *reinterpret_cast<const float2*>(&tmp[m * 512 + t * 2]);
    __shared__ float red[4];
    float s = xv.x + xv.y;
#pragma unroll
    for (int k = 32; k >= 1; k >>= 1) s += __shfl_xor(s, k, 64);
    if (lane == 0) red[wv] = s;
    __syncthreads();
    float mu = (red[0] + red[1] + red[2] + red[3]) * (1.0f / 512.0f);
    __syncthreads();
    float dx = xv.x - mu, dy = xv.y - mu;
    float vs = dx * dx + dy * dy;
#pragma unroll
    for (int k = 32; k >= 1; k >>= 1) vs += __shfl_xor(vs, k, 64);
    if (lane == 0) red[wv] = vs;
    __syncthreads();
    float var = (red[0] + red[1] + red[2] + red[3]) * (1.0f / 512.0f);
    float rstd = rsqrtf(var + 1e-12f);
    float2 g = *reinterpret_cast<const float2*>(&gamma[t * 2]);
    float2 be = *reinterpret_cast<const float2*>(&beta[t * 2]);
    float2 o;
    o.x = dx * rstd * g.x + be.x;
    o.y = dy * rstd * g.y + be.y;
    *reinterpret_cast<float2*>(&out[m * 512 + t * 2]) = o;
}

extern "C" void kernel_launch(void* const* d_in, const int* in_sizes, int n_in,
                              void* d_out, int out_size, void* d_ws, size_t ws_size,
                              hipStream_t stream) {
    const float* x     = (const float*)d_in[0];
    const float* pos   = (const float*)d_in[1];
    const int*   smask = (const int*)d_in[2];
    const float* Wq = (const float*)d_in[3];
    const float* bq = (const float*)d_in[4];
    const float* Wk = (const float*)d_in[5];
    const float* bk = (const float*)d_in[6];
    const float* Wv = (const float*)d_in[7];
    const float* bv = (const float*)d_in[8];
    const float* Wr = (const float*)d_in[9];
    const float* br = (const float*)d_in[10];
    const float* u  = (const float*)d_in[11];
    const float* vb = (const float*)d_in[12];
    const float* Wf = (const float*)d_in[13];
    const float* bf = (const float*)d_in[14];
    const float* gamma = (const float*)d_in[15];
    const float* beta  = (const float*)d_in[16];
    float* out = (float*)d_out;

    float* ws = (float*)d_ws;
    float* q_ws   = ws;                       // 262144
    float* k_ws   = q_ws  + 262144;           // 262144
    float* v_ws   = k_ws  + 262144;           // 262144
    float* w_ws   = v_ws  + 262144;           // 2097152
    float* c_ws   = w_ws  + 2097152;          // 4096
    float* ac_ws  = c_ws  + 4096;             // 1048576
    float* ctx_ws = ac_ws + 1048576;          // 262144
    float* tmp_ws = ctx_ws + 262144;          // 262144
    float* wt_ws  = tmp_ws + 262144;          // 4*262144

    k_transpose<<<dim3(16, 16, 4), 256, 0, stream>>>(Wq, Wk, Wv, Wf, wt_ws);
    k_qkv<<<dim3(2, 64, 3), 256, 0, stream>>>(x, wt_ws, bq, bk, bv, q_ws, k_ws, v_ws);
    k_wgemm<<<dim3(64, 8), 256, 0, stream>>>(q_ws, vb, Wr, br, w_ws, c_ws);
    k_ac<<<dim3(16, 8, 2), 256, 0, stream>>>(q_ws, k_ws, u, c_ws, ac_ws);
    k_attn<<<dim3(512), 512, 0, stream>>>(pos, w_ws, ac_ws, v_ws, smask, ctx_ws);
    k_ffn<<<dim3(2, 64), 256, 0, stream>>>(ctx_ws, wt_ws + 3 * 262144, bf, x, tmp_ws);
    k_ln<<<dim3(512), 256, 0, stream>>>(tmp_ws, gamma, beta, out);
}

// Round 2
// 164.951 us; speedup vs baseline: 1.2217x; 1.2217x over previous
//
#include <hip/hip_runtime.h>
#include <cmath>

typedef __bf16 bf16x8 __attribute__((ext_vector_type(8)));
typedef float f32x4 __attribute__((ext_vector_type(4)));

__device__ __forceinline__ float4 ld4(const float* p) { return *reinterpret_cast<const float4*>(p); }
__device__ __forceinline__ void st4(float* p, float4 v) { *reinterpret_cast<float4*>(p) = v; }
__device__ __forceinline__ void fma4(float4& a, float s, const float4& v) {
    a.x = fmaf(s, v.x, a.x); a.y = fmaf(s, v.y, a.y);
    a.z = fmaf(s, v.z, a.z); a.w = fmaf(s, v.w, a.w);
}
__device__ __forceinline__ float dot4(const float4& a, const float4& b) {
    return a.x*b.x + a.y*b.y + a.z*b.z + a.w*b.w;
}
__device__ __forceinline__ unsigned short f2bf(float f) {
    unsigned int x = __float_as_uint(f);
    unsigned int r = x + 0x7FFFu + ((x >> 16) & 1u);
    return (unsigned short)(r >> 16);
}
__device__ __forceinline__ bf16x8 cvt8(float4 a, float4 b) {
    bf16x8 r;
    r[0] = (__bf16)a.x; r[1] = (__bf16)a.y; r[2] = (__bf16)a.z; r[3] = (__bf16)a.w;
    r[4] = (__bf16)b.x; r[5] = (__bf16)b.y; r[6] = (__bf16)b.z; r[7] = (__bf16)b.w;
    return r;
}

// ---------------- K0: transpose Wq,Wk,Wv,Wf -> Wt[k][n] ----------------
__global__ __launch_bounds__(256) void k_transpose(
        const float* __restrict__ Wq, const float* __restrict__ Wk,
        const float* __restrict__ Wv, const float* __restrict__ Wf,
        float* __restrict__ Wt) {
    __shared__ float tile[32][33];
    int mat = blockIdx.z;
    const float* W = (mat == 0) ? Wq : (mat == 1) ? Wk : (mat == 2) ? Wv : Wf;
    float* out = Wt + mat * 512 * 512;
    int n0 = blockIdx.x * 32, k0 = blockIdx.y * 32;
    int tx = threadIdx.x & 31, ty = threadIdx.x >> 5;
#pragma unroll
    for (int r = 0; r < 4; r++) {
        int row = ty * 4 + r;
        tile[row][tx] = W[(n0 + row) * 512 + k0 + tx];
    }
    __syncthreads();
#pragma unroll
    for (int r = 0; r < 4; r++) {
        int row = ty * 4 + r;
        out[(k0 + row) * 512 + n0 + tx] = tile[tx][row];
    }
}

// ---------------- K1: q/k/v projections ----------------
__global__ __launch_bounds__(256) void k_qkv(
        const float* __restrict__ x, const float* __restrict__ Wt,
        const float* __restrict__ bq, const float* __restrict__ bk, const float* __restrict__ bv,
        float* __restrict__ qw, float* __restrict__ kw, float* __restrict__ vw) {
    int mat = blockIdx.z;
    const float* WT = Wt + mat * 512 * 512;
    const float* bias = (mat == 0) ? bq : (mat == 1) ? bk : bv;
    float* out = (mat == 0) ? qw : (mat == 1) ? kw : vw;
    int n0 = blockIdx.x * 256, m0 = blockIdx.y * 8;
    __shared__ float As[8][512];
    int t = threadIdx.x;
    {
        const float4* src = reinterpret_cast<const float4*>(x + m0 * 512);
        float4* dst = reinterpret_cast<float4*>(&As[0][0]);
#pragma unroll
        for (int r = 0; r < 4; r++) dst[t + r * 256] = src[t + r * 256];
    }
    __syncthreads();
    int n = n0 + (t & 63) * 4;
    int mg = t >> 6;
    int r0 = mg * 2, r1 = r0 + 1;
    float4 acc0 = {0, 0, 0, 0}, acc1 = {0, 0, 0, 0};
    for (int k4 = 0; k4 < 512; k4 += 4) {
        float4 a0 = ld4(&As[r0][k4]);
        float4 a1 = ld4(&As[r1][k4]);
        float4 w0 = ld4(&WT[(k4 + 0) * 512 + n]);
        float4 w1 = ld4(&WT[(k4 + 1) * 512 + n]);
        float4 w2 = ld4(&WT[(k4 + 2) * 512 + n]);
        float4 w3 = ld4(&WT[(k4 + 3) * 512 + n]);
        fma4(acc0, a0.x, w0); fma4(acc0, a0.y, w1); fma4(acc0, a0.z, w2); fma4(acc0, a0.w, w3);
        fma4(acc1, a1.x, w0); fma4(acc1, a1.y, w1); fma4(acc1, a1.z, w2); fma4(acc1, a1.w, w3);
    }
    float4 b4 = ld4(&bias[n]);
    int h = n >> 6, d = n & 63;
    {
        int m = m0 + r0; int b = m >> 8, i = m & 255;
        float4 o; o.x = acc0.x + b4.x; o.y = acc0.y + b4.y; o.z = acc0.z + b4.z; o.w = acc0.w + b4.w;
        st4(out + (((b * 8 + h) * 256 + i) * 64 + d), o);
    }
    {
        int m = m0 + r1; int b = m >> 8, i = m & 255;
        float4 o; o.x = acc1.x + b4.x; o.y = acc1.y + b4.y; o.z = acc1.z + b4.z; o.w = acc1.w + b4.w;
        st4(out + (((b * 8 + h) * 256 + i) * 64 + d), o);
    }
}

// ---------------- K2: w[b,i,h,e] = (q+v).Wr ; pack as bf16 B-fragments ----------------
// w_bf layout per (b,i): [estep 0..15][lane 0..63][elem 0..7] bf16
// where lane = h + 16*grp encodes (h = col, e = estep*32 + grp*8 + elem)
__global__ __launch_bounds__(256) void k_wgemm(
        const float* __restrict__ qw, const float* __restrict__ vbias,
        const float* __restrict__ Wr, const float* __restrict__ br,
        unsigned short* __restrict__ w_bf, float* __restrict__ c_ws) {
    int m0 = blockIdx.x * 8, h = blockIdx.y;
    __shared__ float qv[8][64];
    int t = threadIdx.x;
    {
        int idx = t * 2;
        int r = idx >> 6, d = idx & 63;
        int m = m0 + r; int b = m >> 8, i = m & 255;
        const float* qrow = qw + ((b * 8 + h) * 256 + i) * 64;
        qv[r][d] = qrow[d] + vbias[h * 64 + d];
        qv[r][d + 1] = qrow[d + 1] + vbias[h * 64 + d + 1];
    }
    __syncthreads();
    if (t < 8) {
        float c = 0.f;
        for (int d = 0; d < 64; d++) c += qv[t][d] * br[h * 64 + d];
        int m = m0 + t; int b = m >> 8, i = m & 255;
        c_ws[(b * 8 + h) * 256 + i] = c;
    }
    int el = (t & 127) * 4;
    int mg = t >> 7;
    float4 acc[4] = {{0,0,0,0},{0,0,0,0},{0,0,0,0},{0,0,0,0}};
    for (int d = 0; d < 64; d++) {
        float4 wr4 = ld4(&Wr[(h * 64 + d) * 512 + el]);
#pragma unroll
        for (int r = 0; r < 4; r++) fma4(acc[r], qv[mg * 4 + r][d], wr4);
    }
    int estep = el >> 5, grp = (el >> 3) & 3, sub = el & 7;
    int lane_slot = h + (grp << 4);
#pragma unroll
    for (int r = 0; r < 4; r++) {
        int m = m0 + mg * 4 + r; int b = m >> 8, i = m & 255;
        ushort4 u;
        u.x = f2bf(acc[r].x); u.y = f2bf(acc[r].y); u.z = f2bf(acc[r].z); u.w = f2bf(acc[r].w);
        *reinterpret_cast<ushort4*>(&w_bf[(size_t)(b * 256 + i) * 8192 + estep * 512 + lane_slot * 8 + sub]) = u;
    }
}

// ---------------- K3: AC'[b,h,i,j] = (q+u)_i . k_j + c[b,h,i] ----------------
__global__ __launch_bounds__(256) void k_ac(
        const float* __restrict__ qw, const float* __restrict__ kw,
        const float* __restrict__ u, const float* __restrict__ c_ws,
        float* __restrict__ ac_ws) {
    int i0 = blockIdx.x * 16, h = blockIdx.y, b = blockIdx.z;
    __shared__ float qu[16][64];
    int t = threadIdx.x;
    {
        int idx = t * 4; int r = idx >> 6, d = idx & 63;
        const float* qrow = qw + ((b * 8 + h) * 256 + i0 + r) * 64;
        float4 q4 = ld4(&qrow[d]);
        float4 u4 = ld4(&u[h * 64 + d]);
        float4 o; o.x = q4.x + u4.x; o.y = q4.y + u4.y; o.z = q4.z + u4.z; o.w = q4.w + u4.w;
        st4(&qu[r][d], o);
    }
    __syncthreads();
    int jg = t & 31, ig = t >> 5;
    float acc0[8] = {0,0,0,0,0,0,0,0};
    float acc1[8] = {0,0,0,0,0,0,0,0};
    const float* kbase = kw + (b * 8 + h) * 256 * 64;
    for (int d4 = 0; d4 < 64; d4 += 4) {
        float4 q0 = ld4(&qu[ig * 2 + 0][d4]);
        float4 q1 = ld4(&qu[ig * 2 + 1][d4]);
#pragma unroll
        for (int r = 0; r < 8; r++) {
            int j = jg + r * 32;
            float4 k4 = ld4(&kbase[j * 64 + d4]);
            acc0[r] += dot4(q0, k4);
            acc1[r] += dot4(q1, k4);
        }
    }
    int i_0 = i0 + ig * 2, i_1 = i_0 + 1;
    float c0 = c_ws[(b * 8 + h) * 256 + i_0];
    float c1 = c_ws[(b * 8 + h) * 256 + i_1];
#pragma unroll
    for (int r = 0; r < 8; r++) {
        int j = jg + r * 32;
        ac_ws[((b * 256 + i_0) * 8 + h) * 256 + j] = acc0[r] + c0;
        ac_ws[((b * 256 + i_1) * 8 + h) * 256 + j] = acc1[r] + c1;
    }
}

// ---------------- K4: fused B_D (MFMA) + score + softmax + PV ----------------
// grid 512 = (b,i), block 512 = 8 waves; wave wv covers j-tiles 2wv,2wv+1
__global__ __launch_bounds__(512, 4) void k_attn(
        const float* __restrict__ pos, const unsigned short* __restrict__ w_bf,
        const float* __restrict__ ac_ws, const float* __restrict__ vw,
        const int* __restrict__ seq_mask, float* __restrict__ ctx) {
    int bi = blockIdx.x;
    int b = bi >> 8, i = bi & 255;
    int t = threadIdx.x;
    int wv = t >> 6, lane = t & 63;
    __shared__ float sc[8][260];
    __shared__ float4 part[8][4][16];

    // B-fragments: w for all 16 e-steps (cols 8-15 garbage, ignored)
    const bf16x8* wfrag = reinterpret_cast<const bf16x8*>(w_bf + (size_t)bi * 8192);
    bf16x8 Bf[16];
#pragma unroll
    for (int e = 0; e < 16; e++) Bf[e] = wfrag[e * 64 + lane];

    const float* pbase = pos + (size_t)bi * (256 * 512);
    int arow = lane & 15;
    int eoff = (lane >> 4) * 8;
    const float* pr0 = pbase + (size_t)((wv * 2 + 0) * 16 + arow) * 512 + eoff;
    const float* pr1 = pbase + (size_t)((wv * 2 + 1) * 16 + arow) * 512 + eoff;
    f32x4 acc0 = {0, 0, 0, 0}, acc1 = {0, 0, 0, 0};
    for (int e = 0; e < 16; e += 2) {
        float4 a00 = ld4(pr0 + e * 32), a01 = ld4(pr0 + e * 32 + 4);
        float4 a10 = ld4(pr1 + e * 32), a11 = ld4(pr1 + e * 32 + 4);
        float4 b00 = ld4(pr0 + e * 32 + 32), b01 = ld4(pr0 + e * 32 + 36);
        float4 b10 = ld4(pr1 + e * 32 + 32), b11 = ld4(pr1 + e * 32 + 36);
        acc0 = __builtin_amdgcn_mfma_f32_16x16x32_bf16(cvt8(a00, a01), Bf[e], acc0, 0, 0, 0);
        acc1 = __builtin_amdgcn_mfma_f32_16x16x32_bf16(cvt8(a10, a11), Bf[e], acc1, 0, 0, 0);
        acc0 = __builtin_amdgcn_mfma_f32_16x16x32_bf16(cvt8(b00, b01), Bf[e + 1], acc0, 0, 0, 0);
        acc1 = __builtin_amdgcn_mfma_f32_16x16x32_bf16(cvt8(b10, b11), Bf[e + 1], acc1, 0, 0, 0);
    }
    // C layout: col = lane&15 (= head, 0-7 valid), row = (lane>>4)*4 + r
    {
        int h = lane & 15;
        int rbase = (lane >> 4) * 4;
        if (h < 8) {
#pragma unroll
            for (int r = 0; r < 4; r++) {
                sc[h][(wv * 2 + 0) * 16 + rbase + r] = acc0[r];
                sc[h][(wv * 2 + 1) * 16 + rbase + r] = acc1[r];
            }
        }
    }
    __syncthreads();

    // softmax: wave wv owns head h = wv
    {
        int h = wv;
        const float* acrow = ac_ws + ((b * 256 + i) * 8 + h) * 256;
        float vals[4];
        float mx = -INFINITY;
#pragma unroll
        for (int r = 0; r < 4; r++) {
            int j = lane + r * 64;
            float s = (sc[h][j] + acrow[j]) * 0.125f;
            if (seq_mask[b * 256 + j] == 0) s = -1e15f;
            vals[r] = s;
            mx = fmaxf(mx, s);
        }
#pragma unroll
        for (int m = 32; m >= 1; m >>= 1) mx = fmaxf(mx, __shfl_xor(mx, m, 64));
        float sum = 0.f;
#pragma unroll
        for (int r = 0; r < 4; r++) { vals[r] = __expf(vals[r] - mx); sum += vals[r]; }
#pragma unroll
        for (int m = 32; m >= 1; m >>= 1) sum += __shfl_xor(sum, m, 64);
        float inv = 1.0f / sum;
#pragma unroll
        for (int r = 0; r < 4; r++) sc[h][lane + r * 64] = vals[r] * inv;
    }
    __syncthreads();

    // PV: wave = head; lane -> (jsplit = lane>>4, d4 = (lane&15)*4)
    {
        int h = wv;
        int d4 = (lane & 15) * 4;
        int js = lane >> 4;
        const float* vbase = vw + (size_t)(b * 8 + h) * 256 * 64;
        float4 acc = {0, 0, 0, 0};
        for (int r = 0; r < 64; r++) {
            int j = js * 64 + r;
            float p = sc[h][j];
            float4 v4 = ld4(&vbase[j * 64 + d4]);
            fma4(acc, p, v4);
        }
        part[h][js][lane & 15] = acc;
    }
    __syncthreads();
    {
        int h = wv;
        if ((lane >> 4) == 0) {
            int l = lane & 15;
            float4 a0 = part[h][0][l], a1 = part[h][1][l], a2 = part[h][2][l], a3 = part[h][3][l];
            float4 o;
            o.x = a0.x + a1.x + a2.x + a3.x;
            o.y = a0.y + a1.y + a2.y + a3.y;
            o.z = a0.z + a1.z + a2.z + a3.z;
            o.w = a0.w + a1.w + a2.w + a3.w;
            st4(ctx + (size_t)(b * 256 + i) * 512 + h * 64 + l * 4, o);
        }
    }
}

// ---------------- K5: FFN GEMM + bias + residual ----------------
__global__ __launch_bounds__(256) void k_ffn(
        const float* __restrict__ A, const float* __restrict__ WT,
        const float* __restrict__ bias, const float* __restrict__ resid,
        float* __restrict__ outp) {
    int n0 = blockIdx.x * 256, m0 = blockIdx.y * 8;
    __shared__ float As[8][512];
    int t = threadIdx.x;
    {
        const float4* src = reinterpret_cast<const float4*>(A + m0 * 512);
        float4* dst = reinterpret_cast<float4*>(&As[0][0]);
#pragma unroll
        for (int r = 0; r < 4; r++) dst[t + r * 256] = src[t + r * 256];
    }
    __syncthreads();
    int n = n0 + (t & 63) * 4;
    int mg = t >> 6;
    int r0 = mg * 2, r1 = r0 + 1;
    float4 acc0 = {0, 0, 0, 0}, acc1 = {0, 0, 0, 0};
    for (int k4 = 0; k4 < 512; k4 += 4) {
        float4 a0 = ld4(&As[r0][k4]);
        float4 a1 = ld4(&As[r1][k4]);
        float4 w0 = ld4(&WT[(k4 + 0) * 512 + n]);
        float4 w1 = ld4(&WT[(k4 + 1) * 512 + n]);
        float4 w2 = ld4(&WT[(k4 + 2) * 512 + n]);
        float4 w3 = ld4(&WT[(k4 + 3) * 512 + n]);
        fma4(acc0, a0.x, w0); fma4(acc0, a0.y, w1); fma4(acc0, a0.z, w2); fma4(acc0, a0.w, w3);
        fma4(acc1, a1.x, w0); fma4(acc1, a1.y, w1); fma4(acc1, a1.z, w2); fma4(acc1, a1.w, w3);
    }
    float4 b4 = ld4(&bias[n]);
    {
        int m = m0 + r0;
        float4 res = ld4(&resid[m * 512 + n]);
        float4 o; o.x = acc0.x + b4.x + res.x; o.y = acc0.y + b4.y + res.y;
        o.z = acc0.z + b4.z + res.z; o.w = acc0.w + b4.w + res.w;
        st4(&outp[m * 512 + n], o);
    }
    {
        int m = m0 + r1;
        float4 res = ld4(&resid[m * 512 + n]);
        float4 o; o.x = acc1.x + b4.x + res.x; o.y = acc1.y + b4.y + res.y;
        o.z = acc1.z + b4.z + res.z; o.w = acc1.w + b4.w + res.w;
        st4(&outp[m * 512 + n], o);
    }
}

// ---------------- K6: LayerNorm ----------------
__global__ __launch_bounds__(256) void k_ln(
        const float* __restrict__ tmp, const float* __restrict__ gamma,
        const float* __restrict__ beta, float* __restrict__ out) {
    int m = blockIdx.x, t = threadIdx.x;
    int wv = t >> 6, lane = t & 63;
    float2 xv = *reinterpret_cast<const float2*>(&tmp[m * 512 + t * 2]);
    __shared__ float red[4];
    float s = xv.x + xv.y;
#pragma unroll
    for (int k = 32; k >= 1; k >>= 1) s += __shfl_xor(s, k, 64);
    if (lane == 0) red[wv] = s;
    __syncthreads();
    float mu = (red[0] + red[1] + red[2] + red[3]) * (1.0f / 512.0f);
    __syncthreads();
    float dx = xv.x - mu, dy = xv.y - mu;
    float vs = dx * dx + dy * dy;
#pragma unroll
    for (int k = 32; k >= 1; k >>= 1) vs += __shfl_xor(vs, k, 64);
    if (lane == 0) red[wv] = vs;
    __syncthreads();
    float var = (red[0] + red[1] + red[2] + red[3]) * (1.0f / 512.0f);
    float rstd = rsqrtf(var + 1e-12f);
    float2 g = *reinterpret_cast<const float2*>(&gamma[t * 2]);
    float2 be = *reinterpret_cast<const float2*>(&beta[t * 2]);
    float2 o;
    o.x = dx * rstd * g.x + be.x;
    o.y = dy * rstd * g.y + be.y;
    *reinterpret_cast<float2*>(&out[m * 512 + t * 2]) = o;
}

extern "C" void kernel_launch(void* const* d_in, const int* in_sizes, int n_in,
                              void* d_out, int out_size, void* d_ws, size_t ws_size,
                              hipStream_t stream) {
    const float* x     = (const float*)d_in[0];
    const float* pos   = (const float*)d_in[1];
    const int*   smask = (const int*)d_in[2];
    const float* Wq = (const float*)d_in[3];
    const float* bq = (const float*)d_in[4];
    const float* Wk = (const float*)d_in[5];
    const float* bk = (const float*)d_in[6];
    const float* Wv = (const float*)d_in[7];
    const float* bv = (const float*)d_in[8];
    const float* Wr = (const float*)d_in[9];
    const float* br = (const float*)d_in[10];
    const float* u  = (const float*)d_in[11];
    const float* vb = (const float*)d_in[12];
    const float* Wf = (const float*)d_in[13];
    const float* bf = (const float*)d_in[14];
    const float* gamma = (const float*)d_in[15];
    const float* beta  = (const float*)d_in[16];
    float* out = (float*)d_out;

    float* ws = (float*)d_ws;
    float* q_ws   = ws;                       // 262144 f
    float* k_ws   = q_ws  + 262144;           // 262144 f
    float* v_ws   = k_ws  + 262144;           // 262144 f
    float* w_slot = v_ws  + 262144;           // 2097152 f slot -> holds bf16 pack (8 MB)
    float* c_ws   = w_slot + 2097152;         // 4096 f
    float* ac_ws  = c_ws  + 4096;             // 1048576 f
    float* ctx_ws = ac_ws + 1048576;          // 262144 f
    float* tmp_ws = ctx_ws + 262144;          // 262144 f
    float* wt_ws  = tmp_ws + 262144;          // 4*262144 f
    unsigned short* w_bf = (unsigned short*)w_slot;

    k_transpose<<<dim3(16, 16, 4), 256, 0, stream>>>(Wq, Wk, Wv, Wf, wt_ws);
    k_qkv<<<dim3(2, 64, 3), 256, 0, stream>>>(x, wt_ws, bq, bk, bv, q_ws, k_ws, v_ws);
    k_wgemm<<<dim3(64, 8), 256, 0, stream>>>(q_ws, vb, Wr, br, w_bf, c_ws);
    k_ac<<<dim3(16, 8, 2), 256, 0, stream>>>(q_ws, k_ws, u, c_ws, ac_ws);
    k_attn<<<dim3(512), 512, 0, stream>>>(pos, w_bf, ac_ws, v_ws, smask, ctx_ws);
    k_ffn<<<dim3(2, 64), 256, 0, stream>>>(ctx_ws, wt_ws + 3 * 262144, bf, x, tmp_ws);
    k_ln<<<dim3(512), 256, 0, stream>>>(tmp_ws, gamma, beta, out);
}

// Round 3
// 162.414 us; speedup vs baseline: 1.2407x; 1.0156x over previous
//
#include <hip/hip_runtime.h>
#include <cmath>

typedef __bf16 bf16x8 __attribute__((ext_vector_type(8)));
typedef float f32x4 __attribute__((ext_vector_type(4)));

__device__ __forceinline__ float4 ld4(const float* p) { return *reinterpret_cast<const float4*>(p); }
__device__ __forceinline__ void st4(float* p, float4 v) { *reinterpret_cast<float4*>(p) = v; }
__device__ __forceinline__ void fma4(float4& a, float s, const float4& v) {
    a.x = fmaf(s, v.x, a.x); a.y = fmaf(s, v.y, a.y);
    a.z = fmaf(s, v.z, a.z); a.w = fmaf(s, v.w, a.w);
}
__device__ __forceinline__ float dot4(const float4& a, const float4& b) {
    return a.x*b.x + a.y*b.y + a.z*b.z + a.w*b.w;
}
__device__ __forceinline__ unsigned short f2bf(float f) {
    unsigned int x = __float_as_uint(f);
    unsigned int r = x + 0x7FFFu + ((x >> 16) & 1u);
    return (unsigned short)(r >> 16);
}
__device__ __forceinline__ bf16x8 cvt8(float4 a, float4 b) {
    bf16x8 r;
    r[0] = (__bf16)a.x; r[1] = (__bf16)a.y; r[2] = (__bf16)a.z; r[3] = (__bf16)a.w;
    r[4] = (__bf16)b.x; r[5] = (__bf16)b.y; r[6] = (__bf16)b.z; r[7] = (__bf16)b.w;
    return r;
}

// ---------------- K0: transpose Wq,Wk,Wv,Wf -> Wt[k][n] ----------------
__global__ __launch_bounds__(256) void k_transpose(
        const float* __restrict__ Wq, const float* __restrict__ Wk,
        const float* __restrict__ Wv, const float* __restrict__ Wf,
        float* __restrict__ Wt) {
    __shared__ float tile[32][33];
    int mat = blockIdx.z;
    const float* W = (mat == 0) ? Wq : (mat == 1) ? Wk : (mat == 2) ? Wv : Wf;
    float* out = Wt + mat * 512 * 512;
    int n0 = blockIdx.x * 32, k0 = blockIdx.y * 32;
    int tx = threadIdx.x & 31, ty = threadIdx.x >> 5;
#pragma unroll
    for (int r = 0; r < 4; r++) {
        int row = ty * 4 + r;
        tile[row][tx] = W[(n0 + row) * 512 + k0 + tx];
    }
    __syncthreads();
#pragma unroll
    for (int r = 0; r < 4; r++) {
        int row = ty * 4 + r;
        out[(k0 + row) * 512 + n0 + tx] = tile[tx][row];
    }
}

// ---------------- K1: q/k/v projections ----------------
__global__ __launch_bounds__(256) void k_qkv(
        const float* __restrict__ x, const float* __restrict__ Wt,
        const float* __restrict__ bq, const float* __restrict__ bk, const float* __restrict__ bv,
        float* __restrict__ qw, float* __restrict__ kw, float* __restrict__ vw) {
    int mat = blockIdx.z;
    const float* WT = Wt + mat * 512 * 512;
    const float* bias = (mat == 0) ? bq : (mat == 1) ? bk : bv;
    float* out = (mat == 0) ? qw : (mat == 1) ? kw : vw;
    int n0 = blockIdx.x * 256, m0 = blockIdx.y * 8;
    __shared__ float As[8][512];
    int t = threadIdx.x;
    {
        const float4* src = reinterpret_cast<const float4*>(x + m0 * 512);
        float4* dst = reinterpret_cast<float4*>(&As[0][0]);
#pragma unroll
        for (int r = 0; r < 4; r++) dst[t + r * 256] = src[t + r * 256];
    }
    __syncthreads();
    int n = n0 + (t & 63) * 4;
    int mg = t >> 6;
    int r0 = mg * 2, r1 = r0 + 1;
    float4 acc0 = {0, 0, 0, 0}, acc1 = {0, 0, 0, 0};
    for (int k4 = 0; k4 < 512; k4 += 4) {
        float4 a0 = ld4(&As[r0][k4]);
        float4 a1 = ld4(&As[r1][k4]);
        float4 w0 = ld4(&WT[(k4 + 0) * 512 + n]);
        float4 w1 = ld4(&WT[(k4 + 1) * 512 + n]);
        float4 w2 = ld4(&WT[(k4 + 2) * 512 + n]);
        float4 w3 = ld4(&WT[(k4 + 3) * 512 + n]);
        fma4(acc0, a0.x, w0); fma4(acc0, a0.y, w1); fma4(acc0, a0.z, w2); fma4(acc0, a0.w, w3);
        fma4(acc1, a1.x, w0); fma4(acc1, a1.y, w1); fma4(acc1, a1.z, w2); fma4(acc1, a1.w, w3);
    }
    float4 b4 = ld4(&bias[n]);
    int h = n >> 6, d = n & 63;
    {
        int m = m0 + r0; int b = m >> 8, i = m & 255;
        float4 o; o.x = acc0.x + b4.x; o.y = acc0.y + b4.y; o.z = acc0.z + b4.z; o.w = acc0.w + b4.w;
        st4(out + (((b * 8 + h) * 256 + i) * 64 + d), o);
    }
    {
        int m = m0 + r1; int b = m >> 8, i = m & 255;
        float4 o; o.x = acc1.x + b4.x; o.y = acc1.y + b4.y; o.z = acc1.z + b4.z; o.w = acc1.w + b4.w;
        st4(out + (((b * 8 + h) * 256 + i) * 64 + d), o);
    }
}

// ---------------- K2: w[b,i,h,e] = (q+v)[b,h,i,:] . Wr[h*64:,:] (f32, coalesced) ----------------
__global__ __launch_bounds__(256) void k_wgemm(
        const float* __restrict__ qw, const float* __restrict__ vbias,
        const float* __restrict__ Wr, const float* __restrict__ br,
        float* __restrict__ w_ws, float* __restrict__ c_ws) {
    int m0 = blockIdx.x * 8, h = blockIdx.y;
    __shared__ float qv[8][64];
    int t = threadIdx.x;
    {
        int idx = t * 2;
        int r = idx >> 6, d = idx & 63;
        int m = m0 + r; int b = m >> 8, i = m & 255;
        const float* qrow = qw + ((b * 8 + h) * 256 + i) * 64;
        qv[r][d] = qrow[d] + vbias[h * 64 + d];
        qv[r][d + 1] = qrow[d + 1] + vbias[h * 64 + d + 1];
    }
    __syncthreads();
    if (t < 8) {
        float c = 0.f;
        for (int d = 0; d < 64; d++) c += qv[t][d] * br[h * 64 + d];
        int m = m0 + t; int b = m >> 8, i = m & 255;
        c_ws[(b * 8 + h) * 256 + i] = c;
    }
    int el = (t & 127) * 4;
    int mg = t >> 7;
    float4 acc[4] = {{0,0,0,0},{0,0,0,0},{0,0,0,0},{0,0,0,0}};
    for (int d = 0; d < 64; d++) {
        float4 wr4 = ld4(&Wr[(h * 64 + d) * 512 + el]);
#pragma unroll
        for (int r = 0; r < 4; r++) fma4(acc[r], qv[mg * 4 + r][d], wr4);
    }
#pragma unroll
    for (int r = 0; r < 4; r++) {
        int m = m0 + mg * 4 + r; int b = m >> 8, i = m & 255;
        st4(&w_ws[((size_t)(b * 256 + i) * 8 + h) * 512 + el], acc[r]);
    }
}

// ---------------- K3: AC'[b,h,i,j] = (q+u)_i . k_j + c[b,h,i] ----------------
__global__ __launch_bounds__(256) void k_ac(
        const float* __restrict__ qw, const float* __restrict__ kw,
        const float* __restrict__ u, const float* __restrict__ c_ws,
        float* __restrict__ ac_ws) {
    int i0 = blockIdx.x * 16, h = blockIdx.y, b = blockIdx.z;
    __shared__ float qu[16][64];
    int t = threadIdx.x;
    {
        int idx = t * 4; int r = idx >> 6, d = idx & 63;
        const float* qrow = qw + ((b * 8 + h) * 256 + i0 + r) * 64;
        float4 q4 = ld4(&qrow[d]);
        float4 u4 = ld4(&u[h * 64 + d]);
        float4 o; o.x = q4.x + u4.x; o.y = q4.y + u4.y; o.z = q4.z + u4.z; o.w = q4.w + u4.w;
        st4(&qu[r][d], o);
    }
    __syncthreads();
    int jg = t & 31, ig = t >> 5;
    float acc0[8] = {0,0,0,0,0,0,0,0};
    float acc1[8] = {0,0,0,0,0,0,0,0};
    const float* kbase = kw + (b * 8 + h) * 256 * 64;
    for (int d4 = 0; d4 < 64; d4 += 4) {
        float4 q0 = ld4(&qu[ig * 2 + 0][d4]);
        float4 q1 = ld4(&qu[ig * 2 + 1][d4]);
#pragma unroll
        for (int r = 0; r < 8; r++) {
            int j = jg + r * 32;
            float4 k4 = ld4(&kbase[j * 64 + d4]);
            acc0[r] += dot4(q0, k4);
            acc1[r] += dot4(q1, k4);
        }
    }
    int i_0 = i0 + ig * 2, i_1 = i_0 + 1;
    float c0 = c_ws[(b * 8 + h) * 256 + i_0];
    float c1 = c_ws[(b * 8 + h) * 256 + i_1];
#pragma unroll
    for (int r = 0; r < 8; r++) {
        int j = jg + r * 32;
        ac_ws[((b * 256 + i_0) * 8 + h) * 256 + j] = acc0[r] + c0;
        ac_ws[((b * 256 + i_1) * 8 + h) * 256 + j] = acc1[r] + c1;
    }
}

// ---------------- K4: fused B_D (MFMA, B-frags from LDS) + softmax + PV ----------------
// grid 512 = (b,i), block 512 = 8 waves; wave wv covers j-tiles 2wv,2wv+1
__global__ __launch_bounds__(512, 4) void k_attn(
        const float* __restrict__ pos, const float* __restrict__ w_ws,
        const float* __restrict__ ac_ws, const float* __restrict__ vw,
        const int* __restrict__ seq_mask, float* __restrict__ ctx) {
    int bi = blockIdx.x;
    int b = bi >> 8, i = bi & 255;
    int t = threadIdx.x;
    int wv = t >> 6, lane = t & 63;
    __shared__ float sc[8][260];
    __shared__ float4 part[8][4][16];
    __shared__ unsigned short wl[8 * 520];   // [h][520] shorts, padded for bank spread

    // stage w-tile (f32 -> bf16) into LDS: thread t handles row h = t>>6, 8 elems
    {
        int h = t >> 6;
        int e0 = (t & 63) * 8;
        const float* src = w_ws + ((size_t)bi * 8 + h) * 512 + e0;
        float4 a = ld4(src);
        float4 c = ld4(src + 4);
        ushort4 u0, u1;
        u0.x = f2bf(a.x); u0.y = f2bf(a.y); u0.z = f2bf(a.z); u0.w = f2bf(a.w);
        u1.x = f2bf(c.x); u1.y = f2bf(c.y); u1.z = f2bf(c.z); u1.w = f2bf(c.w);
        *reinterpret_cast<ushort4*>(&wl[h * 520 + e0]) = u0;
        *reinterpret_cast<ushort4*>(&wl[h * 520 + e0 + 4]) = u1;
    }
    __syncthreads();

    // B-fragment source in LDS: lane -> (col h = lane&7 [8-15 broadcast], kgrp g = lane>>4)
    const bf16x8* wfb = reinterpret_cast<const bf16x8*>(&wl[(lane & 7) * 520 + (lane >> 4) * 8]);
    // wfb[e*4] = fragment for e-step e (stride 32 shorts)

    const float* pbase = pos + (size_t)bi * (256 * 512);
    int arow = lane & 15;
    int eoff = (lane >> 4) * 8;
    const float* pr0 = pbase + (size_t)((wv * 2 + 0) * 16 + arow) * 512 + eoff;
    const float* pr1 = pbase + (size_t)((wv * 2 + 1) * 16 + arow) * 512 + eoff;
    f32x4 acc0 = {0, 0, 0, 0}, acc1 = {0, 0, 0, 0};
    for (int e = 0; e < 16; e += 2) {
        float4 a00 = ld4(pr0 + e * 32), a01 = ld4(pr0 + e * 32 + 4);
        float4 a10 = ld4(pr1 + e * 32), a11 = ld4(pr1 + e * 32 + 4);
        float4 b00 = ld4(pr0 + e * 32 + 32), b01 = ld4(pr0 + e * 32 + 36);
        float4 b10 = ld4(pr1 + e * 32 + 32), b11 = ld4(pr1 + e * 32 + 36);
        bf16x8 Bf0 = wfb[e * 4];
        bf16x8 Bf1 = wfb[e * 4 + 4];
        acc0 = __builtin_amdgcn_mfma_f32_16x16x32_bf16(cvt8(a00, a01), Bf0, acc0, 0, 0, 0);
        acc1 = __builtin_amdgcn_mfma_f32_16x16x32_bf16(cvt8(a10, a11), Bf0, acc1, 0, 0, 0);
        acc0 = __builtin_amdgcn_mfma_f32_16x16x32_bf16(cvt8(b00, b01), Bf1, acc0, 0, 0, 0);
        acc1 = __builtin_amdgcn_mfma_f32_16x16x32_bf16(cvt8(b10, b11), Bf1, acc1, 0, 0, 0);
    }
    // C layout: col = lane&15 (= head, 0-7 valid), row = (lane>>4)*4 + r
    {
        int h = lane & 15;
        int rbase = (lane >> 4) * 4;
        if (h < 8) {
#pragma unroll
            for (int r = 0; r < 4; r++) {
                sc[h][(wv * 2 + 0) * 16 + rbase + r] = acc0[r];
                sc[h][(wv * 2 + 1) * 16 + rbase + r] = acc1[r];
            }
        }
    }
    __syncthreads();

    // softmax: wave wv owns head h = wv
    {
        int h = wv;
        const float* acrow = ac_ws + ((b * 256 + i) * 8 + h) * 256;
        float vals[4];
        float mx = -INFINITY;
#pragma unroll
        for (int r = 0; r < 4; r++) {
            int j = lane + r * 64;
            float s = (sc[h][j] + acrow[j]) * 0.125f;
            if (seq_mask[b * 256 + j] == 0) s = -1e15f;
            vals[r] = s;
            mx = fmaxf(mx, s);
        }
#pragma unroll
        for (int m = 32; m >= 1; m >>= 1) mx = fmaxf(mx, __shfl_xor(mx, m, 64));
        float sum = 0.f;
#pragma unroll
        for (int r = 0; r < 4; r++) { vals[r] = __expf(vals[r] - mx); sum += vals[r]; }
#pragma unroll
        for (int m = 32; m >= 1; m >>= 1) sum += __shfl_xor(sum, m, 64);
        float inv = 1.0f / sum;
#pragma unroll
        for (int r = 0; r < 4; r++) sc[h][lane + r * 64] = vals[r] * inv;
    }
    __syncthreads();

    // PV: wave = head; lane -> (jsplit = lane>>4, d4 = (lane&15)*4)
    {
        int h = wv;
        int d4 = (lane & 15) * 4;
        int js = lane >> 4;
        const float* vbase = vw + (size_t)(b * 8 + h) * 256 * 64;
        float4 acc = {0, 0, 0, 0};
        for (int r = 0; r < 64; r++) {
            int j = js * 64 + r;
            float p = sc[h][j];
            float4 v4 = ld4(&vbase[j * 64 + d4]);
            fma4(acc, p, v4);
        }
        part[h][js][lane & 15] = acc;
    }
    __syncthreads();
    {
        int h = wv;
        if ((lane >> 4) == 0) {
            int l = lane & 15;
            float4 a0 = part[h][0][l], a1 = part[h][1][l], a2 = part[h][2][l], a3 = part[h][3][l];
            float4 o;
            o.x = a0.x + a1.x + a2.x + a3.x;
            o.y = a0.y + a1.y + a2.y + a3.y;
            o.z = a0.z + a1.z + a2.z + a3.z;
            o.w = a0.w + a1.w + a2.w + a3.w;
            st4(ctx + (size_t)(b * 256 + i) * 512 + h * 64 + l * 4, o);
        }
    }
}

// ---------------- K5: FFN GEMM + bias + residual ----------------
__global__ __launch_bounds__(256) void k_ffn(
        const float* __restrict__ A, const float* __restrict__ WT,
        const float* __restrict__ bias, const float* __restrict__ resid,
        float* __restrict__ outp) {
    int n0 = blockIdx.x * 256, m0 = blockIdx.y * 8;
    __shared__ float As[8][512];
    int t = threadIdx.x;
    {
        const float4* src = reinterpret_cast<const float4*>(A + m0 * 512);
        float4* dst = reinterpret_cast<float4*>(&As[0][0]);
#pragma unroll
        for (int r = 0; r < 4; r++) dst[t + r * 256] = src[t + r * 256];
    }
    __syncthreads();
    int n = n0 + (t & 63) * 4;
    int mg = t >> 6;
    int r0 = mg * 2, r1 = r0 + 1;
    float4 acc0 = {0, 0, 0, 0}, acc1 = {0, 0, 0, 0};
    for (int k4 = 0; k4 < 512; k4 += 4) {
        float4 a0 = ld4(&As[r0][k4]);
        float4 a1 = ld4(&As[r1][k4]);
        float4 w0 = ld4(&WT[(k4 + 0) * 512 + n]);
        float4 w1 = ld4(&WT[(k4 + 1) * 512 + n]);
        float4 w2 = ld4(&WT[(k4 + 2) * 512 + n]);
        float4 w3 = ld4(&WT[(k4 + 3) * 512 + n]);
        fma4(acc0, a0.x, w0); fma4(acc0, a0.y, w1); fma4(acc0, a0.z, w2); fma4(acc0, a0.w, w3);
        fma4(acc1, a1.x, w0); fma4(acc1, a1.y, w1); fma4(acc1, a1.z, w2); fma4(acc1, a1.w, w3);
    }
    float4 b4 = ld4(&bias[n]);
    {
        int m = m0 + r0;
        float4 res = ld4(&resid[m * 512 + n]);
        float4 o; o.x = acc0.x + b4.x + res.x; o.y = acc0.y + b4.y + res.y;
        o.z = acc0.z + b4.z + res.z; o.w = acc0.w + b4.w + res.w;
        st4(&outp[m * 512 + n], o);
    }
    {
        int m = m0 + r1;
        float4 res = ld4(&resid[m * 512 + n]);
        float4 o; o.x = acc1.x + b4.x + res.x; o.y = acc1.y + b4.y + res.y;
        o.z = acc1.z + b4.z + res.z; o.w = acc1.w + b4.w + res.w;
        st4(&outp[m * 512 + n], o);
    }
}

// ---------------- K6: LayerNorm ----------------
__global__ __launch_bounds__(256) void k_ln(
        const float* __restrict__ tmp, const float* __restrict__ gamma,
        const float* __restrict__ beta, float* __restrict__ out) {
    int m = blockIdx.x, t = threadIdx.x;
    int wv = t >> 6, lane = t & 63;
    float2 xv = *reinterpret_cast<const float2*>(&tmp[m * 512 + t * 2]);
    __shared__ float red[4];
    float s = xv.x + xv.y;
#pragma unroll
    for (int k = 32; k >= 1; k >>= 1) s += __shfl_xor(s, k, 64);
    if (lane == 0) red[wv] = s;
    __syncthreads();
    float mu = (red[0] + red[1] + red[2] + red[3]) * (1.0f / 512.0f);
    __syncthreads();
    float dx = xv.x - mu, dy = xv.y - mu;
    float vs = dx * dx + dy * dy;
#pragma unroll
    for (int k = 32; k >= 1; k >>= 1) vs += __shfl_xor(vs, k, 64);
    if (lane == 0) red[wv] = vs;
    __syncthreads();
    float var = (red[0] + red[1] + red[2] + red[3]) * (1.0f / 512.0f);
    float rstd = rsqrtf(var + 1e-12f);
    float2 g = *reinterpret_cast<const float2*>(&gamma[t * 2]);
    float2 be = *reinterpret_cast<const float2*>(&beta[t * 2]);
    float2 o;
    o.x = dx * rstd * g.x + be.x;
    o.y = dy * rstd * g.y + be.y;
    *reinterpret_cast<float2*>(&out[m * 512 + t * 2]) = o;
}

extern "C" void kernel_launch(void* const* d_in, const int* in_sizes, int n_in,
                              void* d_out, int out_size, void* d_ws, size_t ws_size,
                              hipStream_t stream) {
    const float* x     = (const float*)d_in[0];
    const float* pos   = (const float*)d_in[1];
    const int*   smask = (const int*)d_in[2];
    const float* Wq = (const float*)d_in[3];
    const float* bq = (const float*)d_in[4];
    const float* Wk = (const float*)d_in[5];
    const float* bk = (const float*)d_in[6];
    const float* Wv = (const float*)d_in[7];
    const float* bv = (const float*)d_in[8];
    const float* Wr = (const float*)d_in[9];
    const float* br = (const float*)d_in[10];
    const float* u  = (const float*)d_in[11];
    const float* vb = (const float*)d_in[12];
    const float* Wf = (const float*)d_in[13];
    const float* bf = (const float*)d_in[14];
    const float* gamma = (const float*)d_in[15];
    const float* beta  = (const float*)d_in[16];
    float* out = (float*)d_out;

    float* ws = (float*)d_ws;
    float* q_ws   = ws;                       // 262144 f
    float* k_ws   = q_ws  + 262144;           // 262144 f
    float* v_ws   = k_ws  + 262144;           // 262144 f
    float* w_ws   = v_ws  + 262144;           // 2097152 f
    float* c_ws   = w_ws  + 2097152;          // 4096 f
    float* ac_ws  = c_ws  + 4096;             // 1048576 f
    float* ctx_ws = ac_ws + 1048576;          // 262144 f
    float* tmp_ws = ctx_ws + 262144;          // 262144 f
    float* wt_ws  = tmp_ws + 262144;          // 4*262144 f

    k_transpose<<<dim3(16, 16, 4), 256, 0, stream>>>(Wq, Wk, Wv, Wf, wt_ws);
    k_qkv<<<dim3(2, 64, 3), 256, 0, stream>>>(x, wt_ws, bq, bk, bv, q_ws, k_ws, v_ws);
    k_wgemm<<<dim3(64, 8), 256, 0, stream>>>(q_ws, vb, Wr, br, w_ws, c_ws);
    k_ac<<<dim3(16, 8, 2), 256, 0, stream>>>(q_ws, k_ws, u, c_ws, ac_ws);
    k_attn<<<dim3(512), 512, 0, stream>>>(pos, w_ws, ac_ws, v_ws, smask, ctx_ws);
    k_ffn<<<dim3(2, 64), 256, 0, stream>>>(ctx_ws, wt_ws + 3 * 262144, bf, x, tmp_ws);
    k_ln<<<dim3(512), 256, 0, stream>>>(tmp_ws, gamma, beta, out);
}

// Round 4
// 119.316 us; speedup vs baseline: 1.6889x; 1.3612x over previous
//
#include <hip/hip_runtime.h>
#include <cmath>

typedef __bf16 bf16x8 __attribute__((ext_vector_type(8)));
typedef float f32x4 __attribute__((ext_vector_type(4)));

__device__ __forceinline__ float4 ld4(const float* p) { return *reinterpret_cast<const float4*>(p); }
__device__ __forceinline__ void st4(float* p, float4 v) { *reinterpret_cast<float4*>(p) = v; }
__device__ __forceinline__ void fma4(float4& a, float s, const float4& v) {
    a.x = fmaf(s, v.x, a.x); a.y = fmaf(s, v.y, a.y);
    a.z = fmaf(s, v.z, a.z); a.w = fmaf(s, v.w, a.w);
}
__device__ __forceinline__ float dot4(const float4& a, const float4& b) {
    return a.x*b.x + a.y*b.y + a.z*b.z + a.w*b.w;
}
__device__ __forceinline__ unsigned short f2bf(float f) {
    unsigned int x = __float_as_uint(f);
    unsigned int r = x + 0x7FFFu + ((x >> 16) & 1u);
    return (unsigned short)(r >> 16);
}
__device__ __forceinline__ bf16x8 cvt8(float4 a, float4 b) {
    bf16x8 r;
    r[0] = (__bf16)a.x; r[1] = (__bf16)a.y; r[2] = (__bf16)a.z; r[3] = (__bf16)a.w;
    r[4] = (__bf16)b.x; r[5] = (__bf16)b.y; r[6] = (__bf16)b.z; r[7] = (__bf16)b.w;
    return r;
}

// Core 64x64 MFMA tile: 4 waves, wave wv owns rows [wv*16, wv*16+16) x 64 cols.
// A [Mtile][K] row-major (k-contiguous), B = W [Ntile][K] row-major (k-contiguous).
// acc[c] = C cols [c*16, c*16+16). C map: col=lane&15, row=(lane>>4)*4+r.
__device__ __forceinline__ void mfma_tile(
        const float* __restrict__ Abase, int ldA,
        const float* __restrict__ Bbase, int ldB,
        int K, int lane, f32x4 acc[4]) {
    int koff = (lane >> 4) * 8;
    int rr = lane & 15;
    const float* ap = Abase + rr * ldA + koff;
    const float* bp = Bbase + rr * ldB + koff;
#pragma unroll 2
    for (int k0 = 0; k0 < K; k0 += 32) {
        float4 a0  = ld4(ap + k0),            a1  = ld4(ap + k0 + 4);
        float4 b00 = ld4(bp + k0),            b01 = ld4(bp + k0 + 4);
        float4 b10 = ld4(bp + 16*ldB + k0),   b11 = ld4(bp + 16*ldB + k0 + 4);
        float4 b20 = ld4(bp + 32*ldB + k0),   b21 = ld4(bp + 32*ldB + k0 + 4);
        float4 b30 = ld4(bp + 48*ldB + k0),   b31 = ld4(bp + 48*ldB + k0 + 4);
        bf16x8 af = cvt8(a0, a1);
        acc[0] = __builtin_amdgcn_mfma_f32_16x16x32_bf16(af, cvt8(b00, b01), acc[0], 0, 0, 0);
        acc[1] = __builtin_amdgcn_mfma_f32_16x16x32_bf16(af, cvt8(b10, b11), acc[1], 0, 0, 0);
        acc[2] = __builtin_amdgcn_mfma_f32_16x16x32_bf16(af, cvt8(b20, b21), acc[2], 0, 0, 0);
        acc[3] = __builtin_amdgcn_mfma_f32_16x16x32_bf16(af, cvt8(b30, b31), acc[3], 0, 0, 0);
    }
}

// ---------------- K0: transpose Wr -> Wrt[e][d] ----------------
__global__ __launch_bounds__(256) void k_wrt(
        const float* __restrict__ Wr, float* __restrict__ Wrt) {
    __shared__ float tile[32][33];
    int n0 = blockIdx.x * 32, k0 = blockIdx.y * 32;
    int tx = threadIdx.x & 31, ty = threadIdx.x >> 5;
#pragma unroll
    for (int r = 0; r < 4; r++) {
        int row = ty * 4 + r;
        tile[row][tx] = Wr[(n0 + row) * 512 + k0 + tx];
    }
    __syncthreads();
#pragma unroll
    for (int r = 0; r < 4; r++) {
        int row = ty * 4 + r;
        Wrt[(k0 + row) * 512 + n0 + tx] = tile[tx][row];
    }
}

// ---------------- K1: q/k/v projections (MFMA) ----------------
// grid (8 m-tiles, 8 n-tiles, 3 mats)
__global__ __launch_bounds__(256) void k_qkv(
        const float* __restrict__ x,
        const float* __restrict__ Wq, const float* __restrict__ Wk, const float* __restrict__ Wv,
        const float* __restrict__ bq, const float* __restrict__ bk, const float* __restrict__ bv,
        float* __restrict__ qw, float* __restrict__ kw, float* __restrict__ vw) {
    int mat = blockIdx.z;
    const float* W   = (mat == 0) ? Wq : (mat == 1) ? Wk : Wv;
    const float* bias= (mat == 0) ? bq : (mat == 1) ? bk : bv;
    float* out       = (mat == 0) ? qw : (mat == 1) ? kw : vw;
    int m0 = blockIdx.x * 64, n0 = blockIdx.y * 64;
    int t = threadIdx.x, wv = t >> 6, lane = t & 63;
    f32x4 acc[4] = {{0,0,0,0},{0,0,0,0},{0,0,0,0},{0,0,0,0}};
    mfma_tile(x + (m0 + wv * 16) * 512, 512, W + n0 * 512, 512, 512, lane, acc);
    int h = n0 >> 6;
    int col = lane & 15, rbase = (lane >> 4) * 4;
#pragma unroll
    for (int c = 0; c < 4; c++) {
        int d = c * 16 + col;
        float bv_ = bias[n0 + d];
#pragma unroll
        for (int r = 0; r < 4; r++) {
            int m = m0 + wv * 16 + rbase + r;
            int b = m >> 8, i = m & 255;
            out[((b * 8 + h) * 256 + i) * 64 + d] = acc[c][r] + bv_;
        }
    }
}

// ---------------- K2: small dot terms: c[bhi], uk[bhj], vwr[h,e] ----------------
__global__ __launch_bounds__(256) void k_small(
        const float* __restrict__ qw, const float* __restrict__ kw,
        const float* __restrict__ wrt,
        const float* __restrict__ u, const float* __restrict__ vb,
        const float* __restrict__ br,
        float* __restrict__ c_ws, float* __restrict__ uk_ws, float* __restrict__ vwr_ws) {
    int g = blockIdx.x * 256 + threadIdx.x;
    if (g < 4096) {                 // c[(b*8+h)*256 + i] = (q_i + v_h) . br_h
        int h = (g >> 8) & 7;
        const float* qrow = qw + g * 64;
        const float* brh = br + h * 64;
        const float* vbh = vb + h * 64;
        float s = 0.f;
#pragma unroll
        for (int d = 0; d < 64; d += 4) {
            float4 q4 = ld4(qrow + d), b4 = ld4(brh + d), v4 = ld4(vbh + d);
            s += (q4.x + v4.x) * b4.x + (q4.y + v4.y) * b4.y
               + (q4.z + v4.z) * b4.z + (q4.w + v4.w) * b4.w;
        }
        c_ws[g] = s;
    } else if (g < 8192) {          // uk[(b*8+h)*256 + j] = u_h . k_j
        int g2 = g - 4096;
        int h = (g2 >> 8) & 7;
        const float* krow = kw + g2 * 64;
        const float* uh = u + h * 64;
        float s = 0.f;
#pragma unroll
        for (int d = 0; d < 64; d += 4) s += dot4(ld4(krow + d), ld4(uh + d));
        uk_ws[g2] = s;
    } else if (g < 12288) {         // vwr[h*512 + e] = v_h . Wrt[e][h*64..]
        int g3 = g - 8192;
        int h = g3 >> 9, e = g3 & 511;
        const float* wr_row = wrt + e * 512 + h * 64;
        const float* vbh = vb + h * 64;
        float s = 0.f;
#pragma unroll
        for (int d = 0; d < 64; d += 4) s += dot4(ld4(wr_row + d), ld4(vbh + d));
        vwr_ws[h * 512 + e] = s;
    }
}

// ---------------- K3: w[b,i,h,e] = q . Wrt_h + vwr (MFMA) ----------------
// grid (8 m-tiles, 8 e-tiles, 8 h)
__global__ __launch_bounds__(256) void k_w(
        const float* __restrict__ qw, const float* __restrict__ wrt,
        const float* __restrict__ vwr_ws, float* __restrict__ w_ws) {
    int h = blockIdx.z;
    int m0 = blockIdx.x * 64, n0 = blockIdx.y * 64;
    int t = threadIdx.x, wv = t >> 6, lane = t & 63;
    int b = m0 >> 8, i0 = m0 & 255;
    f32x4 acc[4] = {{0,0,0,0},{0,0,0,0},{0,0,0,0},{0,0,0,0}};
    mfma_tile(qw + ((b * 8 + h) * 256 + i0 + wv * 16) * 64, 64,
              wrt + n0 * 512 + h * 64, 512, 64, lane, acc);
    int col = lane & 15, rbase = (lane >> 4) * 4;
#pragma unroll
    for (int c = 0; c < 4; c++) {
        int n = n0 + c * 16 + col;
        float vw_ = vwr_ws[h * 512 + n];
#pragma unroll
        for (int r = 0; r < 4; r++) {
            int m = m0 + wv * 16 + rbase + r;
            w_ws[((size_t)m * 8 + h) * 512 + n] = acc[c][r] + vw_;
        }
    }
}

// ---------------- K4: ac[b,i,h,j] = q_i.k_j + uk[bhj] + c[bhi] (MFMA) ----------------
// grid (4 i-tiles, 4 j-tiles, 16 bh)
__global__ __launch_bounds__(256) void k_ac(
        const float* __restrict__ qw, const float* __restrict__ kw,
        const float* __restrict__ uk_ws, const float* __restrict__ c_ws,
        float* __restrict__ ac_ws) {
    int bh = blockIdx.z;
    int b = bh >> 3, h = bh & 7;
    int i0 = blockIdx.x * 64, j0 = blockIdx.y * 64;
    int t = threadIdx.x, wv = t >> 6, lane = t & 63;
    f32x4 acc[4] = {{0,0,0,0},{0,0,0,0},{0,0,0,0},{0,0,0,0}};
    mfma_tile(qw + ((b * 8 + h) * 256 + i0 + wv * 16) * 64, 64,
              kw + ((b * 8 + h) * 256 + j0) * 64, 64, 64, lane, acc);
    int col = lane & 15, rbase = (lane >> 4) * 4;
#pragma unroll
    for (int c = 0; c < 4; c++) {
        int j = j0 + c * 16 + col;
        float ukv = uk_ws[(b * 8 + h) * 256 + j];
#pragma unroll
        for (int r = 0; r < 4; r++) {
            int i = i0 + wv * 16 + rbase + r;
            ac_ws[((b * 256 + i) * 8 + h) * 256 + j] = acc[c][r] + ukv + c_ws[(b * 8 + h) * 256 + i];
        }
    }
}

// ---------------- K5: fused B_D (MFMA, B-frags from LDS) + softmax + PV ----------------
// grid 512 = (b,i), block 512 = 8 waves; wave wv covers j-tiles 2wv,2wv+1
__global__ __launch_bounds__(512, 4) void k_attn(
        const float* __restrict__ pos, const float* __restrict__ w_ws,
        const float* __restrict__ ac_ws, const float* __restrict__ vw,
        const int* __restrict__ seq_mask, float* __restrict__ ctx) {
    int bi = blockIdx.x;
    int b = bi >> 8, i = bi & 255;
    int t = threadIdx.x;
    int wv = t >> 6, lane = t & 63;
    __shared__ float sc[8][260];
    __shared__ float4 part[8][4][16];
    __shared__ unsigned short wl[8 * 520];

    // stage w-tile (f32 -> bf16) into LDS
    {
        int h = t >> 6;
        int e0 = (t & 63) * 8;
        const float* src = w_ws + ((size_t)bi * 8 + h) * 512 + e0;
        float4 a = ld4(src);
        float4 c = ld4(src + 4);
        ushort4 u0, u1;
        u0.x = f2bf(a.x); u0.y = f2bf(a.y); u0.z = f2bf(a.z); u0.w = f2bf(a.w);
        u1.x = f2bf(c.x); u1.y = f2bf(c.y); u1.z = f2bf(c.z); u1.w = f2bf(c.w);
        *reinterpret_cast<ushort4*>(&wl[h * 520 + e0]) = u0;
        *reinterpret_cast<ushort4*>(&wl[h * 520 + e0 + 4]) = u1;
    }
    __syncthreads();

    const bf16x8* wfb = reinterpret_cast<const bf16x8*>(&wl[(lane & 7) * 520 + (lane >> 4) * 8]);

    const float* pbase = pos + (size_t)bi * (256 * 512);
    int arow = lane & 15;
    int eoff = (lane >> 4) * 8;
    const float* pr0 = pbase + (size_t)((wv * 2 + 0) * 16 + arow) * 512 + eoff;
    const float* pr1 = pbase + (size_t)((wv * 2 + 1) * 16 + arow) * 512 + eoff;
    f32x4 acc0 = {0, 0, 0, 0}, acc1 = {0, 0, 0, 0};
    for (int e = 0; e < 16; e += 2) {
        float4 a00 = ld4(pr0 + e * 32), a01 = ld4(pr0 + e * 32 + 4);
        float4 a10 = ld4(pr1 + e * 32), a11 = ld4(pr1 + e * 32 + 4);
        float4 b00 = ld4(pr0 + e * 32 + 32), b01 = ld4(pr0 + e * 32 + 36);
        float4 b10 = ld4(pr1 + e * 32 + 32), b11 = ld4(pr1 + e * 32 + 36);
        bf16x8 Bf0 = wfb[e * 4];
        bf16x8 Bf1 = wfb[e * 4 + 4];
        acc0 = __builtin_amdgcn_mfma_f32_16x16x32_bf16(cvt8(a00, a01), Bf0, acc0, 0, 0, 0);
        acc1 = __builtin_amdgcn_mfma_f32_16x16x32_bf16(cvt8(a10, a11), Bf0, acc1, 0, 0, 0);
        acc0 = __builtin_amdgcn_mfma_f32_16x16x32_bf16(cvt8(b00, b01), Bf1, acc0, 0, 0, 0);
        acc1 = __builtin_amdgcn_mfma_f32_16x16x32_bf16(cvt8(b10, b11), Bf1, acc1, 0, 0, 0);
    }
    {
        int h = lane & 15;
        int rbase = (lane >> 4) * 4;
        if (h < 8) {
#pragma unroll
            for (int r = 0; r < 4; r++) {
                sc[h][(wv * 2 + 0) * 16 + rbase + r] = acc0[r];
                sc[h][(wv * 2 + 1) * 16 + rbase + r] = acc1[r];
            }
        }
    }
    __syncthreads();

    // softmax: wave wv owns head h = wv
    {
        int h = wv;
        const float* acrow = ac_ws + ((b * 256 + i) * 8 + h) * 256;
        float vals[4];
        float mx = -INFINITY;
#pragma unroll
        for (int r = 0; r < 4; r++) {
            int j = lane + r * 64;
            float s = (sc[h][j] + acrow[j]) * 0.125f;
            if (seq_mask[b * 256 + j] == 0) s = -1e15f;
            vals[r] = s;
            mx = fmaxf(mx, s);
        }
#pragma unroll
        for (int m = 32; m >= 1; m >>= 1) mx = fmaxf(mx, __shfl_xor(mx, m, 64));
        float sum = 0.f;
#pragma unroll
        for (int r = 0; r < 4; r++) { vals[r] = __expf(vals[r] - mx); sum += vals[r]; }
#pragma unroll
        for (int m = 32; m >= 1; m >>= 1) sum += __shfl_xor(sum, m, 64);
        float inv = 1.0f / sum;
#pragma unroll
        for (int r = 0; r < 4; r++) sc[h][lane + r * 64] = vals[r] * inv;
    }
    __syncthreads();

    // PV
    {
        int h = wv;
        int d4 = (lane & 15) * 4;
        int js = lane >> 4;
        const float* vbase = vw + (size_t)(b * 8 + h) * 256 * 64;
        float4 acc = {0, 0, 0, 0};
        for (int r = 0; r < 64; r++) {
            int j = js * 64 + r;
            float p = sc[h][j];
            float4 v4 = ld4(&vbase[j * 64 + d4]);
            fma4(acc, p, v4);
        }
        part[h][js][lane & 15] = acc;
    }
    __syncthreads();
    {
        int h = wv;
        if ((lane >> 4) == 0) {
            int l = lane & 15;
            float4 a0 = part[h][0][l], a1 = part[h][1][l], a2 = part[h][2][l], a3 = part[h][3][l];
            float4 o;
            o.x = a0.x + a1.x + a2.x + a3.x;
            o.y = a0.y + a1.y + a2.y + a3.y;
            o.z = a0.z + a1.z + a2.z + a3.z;
            o.w = a0.w + a1.w + a2.w + a3.w;
            st4(ctx + (size_t)(b * 256 + i) * 512 + h * 64 + l * 4, o);
        }
    }
}

// ---------------- K6: FFN GEMM + bias + residual (MFMA) ----------------
// grid (8 m-tiles, 8 n-tiles)
__global__ __launch_bounds__(256) void k_ffn(
        const float* __restrict__ A, const float* __restrict__ Wf,
        const float* __restrict__ bias, const float* __restrict__ resid,
        float* __restrict__ outp) {
    int m0 = blockIdx.x * 64, n0 = blockIdx.y * 64;
    int t = threadIdx.x, wv = t >> 6, lane = t & 63;
    f32x4 acc[4] = {{0,0,0,0},{0,0,0,0},{0,0,0,0},{0,0,0,0}};
    mfma_tile(A + (m0 + wv * 16) * 512, 512, Wf + n0 * 512, 512, 512, lane, acc);
    int col = lane & 15, rbase = (lane >> 4) * 4;
#pragma unroll
    for (int c = 0; c < 4; c++) {
        int n = n0 + c * 16 + col;
        float bv_ = bias[n];
#pragma unroll
        for (int r = 0; r < 4; r++) {
            int m = m0 + wv * 16 + rbase + r;
            outp[m * 512 + n] = acc[c][r] + bv_ + resid[m * 512 + n];
        }
    }
}

// ---------------- K7: LayerNorm ----------------
__global__ __launch_bounds__(256) void k_ln(
        const float* __restrict__ tmp, const float* __restrict__ gamma,
        const float* __restrict__ beta, float* __restrict__ out) {
    int m = blockIdx.x, t = threadIdx.x;
    int wv = t >> 6, lane = t & 63;
    float2 xv = *reinterpret_cast<const float2*>(&tmp[m * 512 + t * 2]);
    __shared__ float red[4];
    float s = xv.x + xv.y;
#pragma unroll
    for (int k = 32; k >= 1; k >>= 1) s += __shfl_xor(s, k, 64);
    if (lane == 0) red[wv] = s;
    __syncthreads();
    float mu = (red[0] + red[1] + red[2] + red[3]) * (1.0f / 512.0f);
    __syncthreads();
    float dx = xv.x - mu, dy = xv.y - mu;
    float vs = dx * dx + dy * dy;
#pragma unroll
    for (int k = 32; k >= 1; k >>= 1) vs += __shfl_xor(vs, k, 64);
    if (lane == 0) red[wv] = vs;
    __syncthreads();
    float var = (red[0] + red[1] + red[2] + red[3]) * (1.0f / 512.0f);
    float rstd = rsqrtf(var + 1e-12f);
    float2 g = *reinterpret_cast<const float2*>(&gamma[t * 2]);
    float2 be = *reinterpret_cast<const float2*>(&beta[t * 2]);
    float2 o;
    o.x = dx * rstd * g.x + be.x;
    o.y = dy * rstd * g.y + be.y;
    *reinterpret_cast<float2*>(&out[m * 512 + t * 2]) = o;
}

extern "C" void kernel_launch(void* const* d_in, const int* in_sizes, int n_in,
                              void* d_out, int out_size, void* d_ws, size_t ws_size,
                              hipStream_t stream) {
    const float* x     = (const float*)d_in[0];
    const float* pos   = (const float*)d_in[1];
    const int*   smask = (const int*)d_in[2];
    const float* Wq = (const float*)d_in[3];
    const float* bq = (const float*)d_in[4];
    const float* Wk = (const float*)d_in[5];
    const float* bk = (const float*)d_in[6];
    const float* Wv = (const float*)d_in[7];
    const float* bv = (const float*)d_in[8];
    const float* Wr = (const float*)d_in[9];
    const float* br = (const float*)d_in[10];
    const float* u  = (const float*)d_in[11];
    const float* vb = (const float*)d_in[12];
    const float* Wf = (const float*)d_in[13];
    const float* bf = (const float*)d_in[14];
    const float* gamma = (const float*)d_in[15];
    const float* beta  = (const float*)d_in[16];
    float* out = (float*)d_out;

    float* ws = (float*)d_ws;
    float* q_ws   = ws;                       // 262144 f
    float* k_ws   = q_ws  + 262144;           // 262144 f
    float* v_ws   = k_ws  + 262144;           // 262144 f
    float* w_ws   = v_ws  + 262144;           // 2097152 f
    float* c_ws   = w_ws  + 2097152;          // 4096 f
    float* uk_ws  = c_ws  + 4096;             // 4096 f
    float* vwr_ws = uk_ws + 4096;             // 4096 f
    float* ac_ws  = vwr_ws + 4096;            // 1048576 f
    float* ctx_ws = ac_ws + 1048576;          // 262144 f
    float* tmp_ws = ctx_ws + 262144;          // 262144 f
    float* wrt_ws = tmp_ws + 262144;          // 262144 f

    k_wrt<<<dim3(16, 16), 256, 0, stream>>>(Wr, wrt_ws);
    k_qkv<<<dim3(8, 8, 3), 256, 0, stream>>>(x, Wq, Wk, Wv, bq, bk, bv, q_ws, k_ws, v_ws);
    k_small<<<dim3(48), 256, 0, stream>>>(q_ws, k_ws, wrt_ws, u, vb, br, c_ws, uk_ws, vwr_ws);
    k_w<<<dim3(8, 8, 8), 256, 0, stream>>>(q_ws, wrt_ws, vwr_ws, w_ws);
    k_ac<<<dim3(4, 4, 16), 256, 0, stream>>>(q_ws, k_ws, uk_ws, c_ws, ac_ws);
    k_attn<<<dim3(512), 512, 0, stream>>>(pos, w_ws, ac_ws, v_ws, smask, ctx_ws);
    k_ffn<<<dim3(8, 8), 256, 0, stream>>>(ctx_ws, Wf, bf, x, tmp_ws);
    k_ln<<<dim3(512), 256, 0, stream>>>(tmp_ws, gamma, beta, out);
}

// Round 5
// 117.303 us; speedup vs baseline: 1.7179x; 1.0172x over previous
//
#include <hip/hip_runtime.h>
#include <cmath>

typedef __bf16 bf16x8 __attribute__((ext_vector_type(8)));
typedef float f32x4 __attribute__((ext_vector_type(4)));

__device__ __forceinline__ float4 ld4(const float* p) { return *reinterpret_cast<const float4*>(p); }
__device__ __forceinline__ void st4(float* p, float4 v) { *reinterpret_cast<float4*>(p) = v; }
__device__ __forceinline__ void fma4(float4& a, float s, const float4& v) {
    a.x = fmaf(s, v.x, a.x); a.y = fmaf(s, v.y, a.y);
    a.z = fmaf(s, v.z, a.z); a.w = fmaf(s, v.w, a.w);
}
__device__ __forceinline__ float dot4(const float4& a, const float4& b) {
    return a.x*b.x + a.y*b.y + a.z*b.z + a.w*b.w;
}
__device__ __forceinline__ unsigned short f2bf(float f) {
    unsigned int x = __float_as_uint(f);
    unsigned int r = x + 0x7FFFu + ((x >> 16) & 1u);
    return (unsigned short)(r >> 16);
}
__device__ __forceinline__ ushort4 cvt4u(float4 a) {
    ushort4 u;
    u.x = f2bf(a.x); u.y = f2bf(a.y); u.z = f2bf(a.z); u.w = f2bf(a.w);
    return u;
}
__device__ __forceinline__ bf16x8 cvt8(float4 a, float4 b) {
    bf16x8 r;
    r[0] = (__bf16)a.x; r[1] = (__bf16)a.y; r[2] = (__bf16)a.z; r[3] = (__bf16)a.w;
    r[4] = (__bf16)b.x; r[5] = (__bf16)b.y; r[6] = (__bf16)b.z; r[7] = (__bf16)b.w;
    return r;
}

// Core 64x64 MFMA tile: 4 waves, wave wv owns rows [wv*16, wv*16+16) x 64 cols.
__device__ __forceinline__ void mfma_tile(
        const float* __restrict__ Abase, int ldA,
        const float* __restrict__ Bbase, int ldB,
        int K, int lane, f32x4 acc[4]) {
    int koff = (lane >> 4) * 8;
    int rr = lane & 15;
    const float* ap = Abase + rr * ldA + koff;
    const float* bp = Bbase + rr * ldB + koff;
#pragma unroll 2
    for (int k0 = 0; k0 < K; k0 += 32) {
        float4 a0  = ld4(ap + k0),            a1  = ld4(ap + k0 + 4);
        float4 b00 = ld4(bp + k0),            b01 = ld4(bp + k0 + 4);
        float4 b10 = ld4(bp + 16*ldB + k0),   b11 = ld4(bp + 16*ldB + k0 + 4);
        float4 b20 = ld4(bp + 32*ldB + k0),   b21 = ld4(bp + 32*ldB + k0 + 4);
        float4 b30 = ld4(bp + 48*ldB + k0),   b31 = ld4(bp + 48*ldB + k0 + 4);
        bf16x8 af = cvt8(a0, a1);
        acc[0] = __builtin_amdgcn_mfma_f32_16x16x32_bf16(af, cvt8(b00, b01), acc[0], 0, 0, 0);
        acc[1] = __builtin_amdgcn_mfma_f32_16x16x32_bf16(af, cvt8(b10, b11), acc[1], 0, 0, 0);
        acc[2] = __builtin_amdgcn_mfma_f32_16x16x32_bf16(af, cvt8(b20, b21), acc[2], 0, 0, 0);
        acc[3] = __builtin_amdgcn_mfma_f32_16x16x32_bf16(af, cvt8(b30, b31), acc[3], 0, 0, 0);
    }
}

// ---------------- K0: transpose Wr -> Wrt[e][d] ----------------
__global__ __launch_bounds__(256) void k_wrt(
        const float* __restrict__ Wr, float* __restrict__ Wrt) {
    __shared__ float tile[32][33];
    int n0 = blockIdx.x * 32, k0 = blockIdx.y * 32;
    int tx = threadIdx.x & 31, ty = threadIdx.x >> 5;
#pragma unroll
    for (int r = 0; r < 4; r++) {
        int row = ty * 4 + r;
        tile[row][tx] = Wr[(n0 + row) * 512 + k0 + tx];
    }
    __syncthreads();
#pragma unroll
    for (int r = 0; r < 4; r++) {
        int row = ty * 4 + r;
        Wrt[(k0 + row) * 512 + n0 + tx] = tile[tx][row];
    }
}

// ---------------- K1: q/k/v projections (MFMA) ----------------
__global__ __launch_bounds__(256) void k_qkv(
        const float* __restrict__ x,
        const float* __restrict__ Wq, const float* __restrict__ Wk, const float* __restrict__ Wv,
        const float* __restrict__ bq, const float* __restrict__ bk, const float* __restrict__ bv,
        float* __restrict__ qw, float* __restrict__ kw, float* __restrict__ vw) {
    int mat = blockIdx.z;
    const float* W   = (mat == 0) ? Wq : (mat == 1) ? Wk : Wv;
    const float* bias= (mat == 0) ? bq : (mat == 1) ? bk : bv;
    float* out       = (mat == 0) ? qw : (mat == 1) ? kw : vw;
    int m0 = blockIdx.x * 64, n0 = blockIdx.y * 64;
    int t = threadIdx.x, wv = t >> 6, lane = t & 63;
    f32x4 acc[4] = {{0,0,0,0},{0,0,0,0},{0,0,0,0},{0,0,0,0}};
    mfma_tile(x + (m0 + wv * 16) * 512, 512, W + n0 * 512, 512, 512, lane, acc);
    int h = n0 >> 6;
    int col = lane & 15, rbase = (lane >> 4) * 4;
#pragma unroll
    for (int c = 0; c < 4; c++) {
        int d = c * 16 + col;
        float bv_ = bias[n0 + d];
#pragma unroll
        for (int r = 0; r < 4; r++) {
            int m = m0 + wv * 16 + rbase + r;
            int b = m >> 8, i = m & 255;
            out[((b * 8 + h) * 256 + i) * 64 + d] = acc[c][r] + bv_;
        }
    }
}

// ---------------- K2: small dot terms: c[bhi], uk[bhj], vwr[h,e] ----------------
__global__ __launch_bounds__(256) void k_small(
        const float* __restrict__ qw, const float* __restrict__ kw,
        const float* __restrict__ wrt,
        const float* __restrict__ u, const float* __restrict__ vb,
        const float* __restrict__ br,
        float* __restrict__ c_ws, float* __restrict__ uk_ws, float* __restrict__ vwr_ws) {
    int g = blockIdx.x * 256 + threadIdx.x;
    if (g < 4096) {
        int h = (g >> 8) & 7;
        const float* qrow = qw + g * 64;
        const float* brh = br + h * 64;
        const float* vbh = vb + h * 64;
        float s = 0.f;
#pragma unroll
        for (int d = 0; d < 64; d += 4) {
            float4 q4 = ld4(qrow + d), b4 = ld4(brh + d), v4 = ld4(vbh + d);
            s += (q4.x + v4.x) * b4.x + (q4.y + v4.y) * b4.y
               + (q4.z + v4.z) * b4.z + (q4.w + v4.w) * b4.w;
        }
        c_ws[g] = s;
    } else if (g < 8192) {
        int g2 = g - 4096;
        int h = (g2 >> 8) & 7;
        const float* krow = kw + g2 * 64;
        const float* uh = u + h * 64;
        float s = 0.f;
#pragma unroll
        for (int d = 0; d < 64; d += 4) s += dot4(ld4(krow + d), ld4(uh + d));
        uk_ws[g2] = s;
    } else if (g < 12288) {
        int g3 = g - 8192;
        int h = g3 >> 9, e = g3 & 511;
        const float* wr_row = wrt + e * 512 + h * 64;
        const float* vbh = vb + h * 64;
        float s = 0.f;
#pragma unroll
        for (int d = 0; d < 64; d += 4) s += dot4(ld4(wr_row + d), ld4(vbh + d));
        vwr_ws[h * 512 + e] = s;
    }
}

// ---------------- K3: w[b,i,h,e] = q . Wrt_h + vwr (MFMA) ----------------
__global__ __launch_bounds__(256) void k_w(
        const float* __restrict__ qw, const float* __restrict__ wrt,
        const float* __restrict__ vwr_ws, float* __restrict__ w_ws) {
    int h = blockIdx.z;
    int m0 = blockIdx.x * 64, n0 = blockIdx.y * 64;
    int t = threadIdx.x, wv = t >> 6, lane = t & 63;
    int b = m0 >> 8, i0 = m0 & 255;
    f32x4 acc[4] = {{0,0,0,0},{0,0,0,0},{0,0,0,0},{0,0,0,0}};
    mfma_tile(qw + ((b * 8 + h) * 256 + i0 + wv * 16) * 64, 64,
              wrt + n0 * 512 + h * 64, 512, 64, lane, acc);
    int col = lane & 15, rbase = (lane >> 4) * 4;
#pragma unroll
    for (int c = 0; c < 4; c++) {
        int n = n0 + c * 16 + col;
        float vw_ = vwr_ws[h * 512 + n];
#pragma unroll
        for (int r = 0; r < 4; r++) {
            int m = m0 + wv * 16 + rbase + r;
            w_ws[((size_t)m * 8 + h) * 512 + n] = acc[c][r] + vw_;
        }
    }
}

// ---------------- K4: ac[b,i,h,j] = q_i.k_j + uk[bhj] + c[bhi] (MFMA) ----------------
__global__ __launch_bounds__(256) void k_ac(
        const float* __restrict__ qw, const float* __restrict__ kw,
        const float* __restrict__ uk_ws, const float* __restrict__ c_ws,
        float* __restrict__ ac_ws) {
    int bh = blockIdx.z;
    int b = bh >> 3, h = bh & 7;
    int i0 = blockIdx.x * 64, j0 = blockIdx.y * 64;
    int t = threadIdx.x, wv = t >> 6, lane = t & 63;
    f32x4 acc[4] = {{0,0,0,0},{0,0,0,0},{0,0,0,0},{0,0,0,0}};
    mfma_tile(qw + ((b * 8 + h) * 256 + i0 + wv * 16) * 64, 64,
              kw + ((b * 8 + h) * 256 + j0) * 64, 64, 64, lane, acc);
    int col = lane & 15, rbase = (lane >> 4) * 4;
#pragma unroll
    for (int c = 0; c < 4; c++) {
        int j = j0 + c * 16 + col;
        float ukv = uk_ws[(b * 8 + h) * 256 + j];
#pragma unroll
        for (int r = 0; r < 4; r++) {
            int i = i0 + wv * 16 + rbase + r;
            ac_ws[((b * 256 + i) * 8 + h) * 256 + j] = acc[c][r] + ukv + c_ws[(b * 8 + h) * 256 + i];
        }
    }
}

// ---------------- K5: fused B_D (LDS-staged MFMA) + softmax + PV ----------------
// grid 512 = (b,i), block 512 = 8 waves; wave wv owns j-rows [32wv, 32wv+32)
__global__ __launch_bounds__(512, 4) void k_attn(
        const float* __restrict__ pos, const float* __restrict__ w_ws,
        const float* __restrict__ ac_ws, const float* __restrict__ vw,
        const int* __restrict__ seq_mask, float* __restrict__ ctx) {
    int bi = blockIdx.x;
    int b = bi >> 8, i = bi & 255;
    int t = threadIdx.x;
    int wv = t >> 6, lane = t & 63;
    __shared__ unsigned short wl[8 * 512];       // 8 KB  w B-frags (bf16)
    __shared__ float sc[8][256];                 // 8 KB  scores -> attn
    __shared__ unsigned short stage[8][4096];    // 64 KB wave-private staging; PV partials overlay

    // stage w (f32 -> bf16) into wl
    {
        int h = t >> 6;
        int e0 = (t & 63) * 8;
        const float* src = w_ws + ((size_t)bi * 8 + h) * 512 + e0;
        float4 a = ld4(src);
        float4 c = ld4(src + 4);
        *reinterpret_cast<ushort4*>(&wl[h * 512 + e0])     = cvt4u(a);
        *reinterpret_cast<ushort4*>(&wl[h * 512 + e0 + 4]) = cvt4u(c);
    }
    __syncthreads();

    const float* pb = pos + (size_t)bi * (256 * 512);
    int jbase = wv * 32;
    unsigned short* sb = &stage[wv][0];
    int arow = lane & 15;
    int koff = (lane >> 4) * 8;

#pragma unroll
    for (int jt = 0; jt < 2; jt++) {
        f32x4 acc = {0, 0, 0, 0};
#pragma unroll
        for (int eh = 0; eh < 2; eh++) {
            // stage 16 rows x 256 e: per step, wave reads 1 KB contiguous
            const float* src = pb + (size_t)(jbase + jt * 16) * 512 + eh * 256 + lane * 4;
            float4 tmp[16];
#pragma unroll
            for (int s = 0; s < 16; s++) tmp[s] = ld4(src + s * 512);
#pragma unroll
            for (int s = 0; s < 16; s++) {
                *reinterpret_cast<ushort4*>(&sb[s * 256 + lane * 4]) = cvt4u(tmp[s]);
            }
            // 8 accumulating MFMA e-steps
#pragma unroll
            for (int es = 0; es < 8; es++) {
                bf16x8 af = *reinterpret_cast<const bf16x8*>(&sb[arow * 256 + es * 32 + koff]);
                bf16x8 bf = *reinterpret_cast<const bf16x8*>(&wl[(lane & 7) * 512 + (eh * 8 + es) * 32 + koff]);
                acc = __builtin_amdgcn_mfma_f32_16x16x32_bf16(af, bf, acc, 0, 0, 0);
            }
        }
        // scores: C col = lane&15 (= head, 0-7 valid), row = (lane>>4)*4 + r
        int h = lane & 15;
        int rbase = (lane >> 4) * 4;
        if (h < 8) {
#pragma unroll
            for (int r = 0; r < 4; r++) sc[h][jbase + jt * 16 + rbase + r] = acc[r];
        }
    }
    __syncthreads();

    // softmax: wave wv owns head h = wv
    {
        int h = wv;
        const float* acrow = ac_ws + ((b * 256 + i) * 8 + h) * 256;
        float vals[4];
        float mx = -INFINITY;
#pragma unroll
        for (int r = 0; r < 4; r++) {
            int j = lane + r * 64;
            float s = (sc[h][j] + acrow[j]) * 0.125f;
            if (seq_mask[b * 256 + j] == 0) s = -1e15f;
            vals[r] = s;
            mx = fmaxf(mx, s);
        }
#pragma unroll
        for (int m = 32; m >= 1; m >>= 1) mx = fmaxf(mx, __shfl_xor(mx, m, 64));
        float sum = 0.f;
#pragma unroll
        for (int r = 0; r < 4; r++) { vals[r] = __expf(vals[r] - mx); sum += vals[r]; }
#pragma unroll
        for (int m = 32; m >= 1; m >>= 1) sum += __shfl_xor(sum, m, 64);
        float inv = 1.0f / sum;
#pragma unroll
        for (int r = 0; r < 4; r++) sc[h][lane + r * 64] = vals[r] * inv;
    }
    // no barrier needed: PV uses wave-private data (sc row h by wave h; part overlay region h)

    // PV: wave = head; lane -> (jsplit = lane>>4, d4 = (lane&15)*4)
    float4* part = reinterpret_cast<float4*>(&stage[0][0]);  // [8][4][16] float4 overlay
    {
        int h = wv;
        int d4 = (lane & 15) * 4;
        int js = lane >> 4;
        const float* vbase = vw + (size_t)(b * 8 + h) * 256 * 64;
        float4 acc = {0, 0, 0, 0};
        for (int r = 0; r < 64; r++) {
            int j = js * 64 + r;
            float p = sc[h][j];
            float4 v4 = ld4(&vbase[j * 64 + d4]);
            fma4(acc, p, v4);
        }
        part[(h * 4 + js) * 16 + (lane & 15)] = acc;
    }
    {
        int h = wv;
        if ((lane >> 4) == 0) {
            int l = lane & 15;
            float4 a0 = part[(h * 4 + 0) * 16 + l], a1 = part[(h * 4 + 1) * 16 + l];
            float4 a2 = part[(h * 4 + 2) * 16 + l], a3 = part[(h * 4 + 3) * 16 + l];
            float4 o;
            o.x = a0.x + a1.x + a2.x + a3.x;
            o.y = a0.y + a1.y + a2.y + a3.y;
            o.z = a0.z + a1.z + a2.z + a3.z;
            o.w = a0.w + a1.w + a2.w + a3.w;
            st4(ctx + (size_t)(b * 256 + i) * 512 + h * 64 + l * 4, o);
        }
    }
}

// ---------------- K6: FFN GEMM + bias + residual (MFMA) ----------------
__global__ __launch_bounds__(256) void k_ffn(
        const float* __restrict__ A, const float* __restrict__ Wf,
        const float* __restrict__ bias, const float* __restrict__ resid,
        float* __restrict__ outp) {
    int m0 = blockIdx.x * 64, n0 = blockIdx.y * 64;
    int t = threadIdx.x, wv = t >> 6, lane = t & 63;
    f32x4 acc[4] = {{0,0,0,0},{0,0,0,0},{0,0,0,0},{0,0,0,0}};
    mfma_tile(A + (m0 + wv * 16) * 512, 512, Wf + n0 * 512, 512, 512, lane, acc);
    int col = lane & 15, rbase = (lane >> 4) * 4;
#pragma unroll
    for (int c = 0; c < 4; c++) {
        int n = n0 + c * 16 + col;
        float bv_ = bias[n];
#pragma unroll
        for (int r = 0; r < 4; r++) {
            int m = m0 + wv * 16 + rbase + r;
            outp[m * 512 + n] = acc[c][r] + bv_ + resid[m * 512 + n];
        }
    }
}

// ---------------- K7: LayerNorm ----------------
__global__ __launch_bounds__(256) void k_ln(
        const float* __restrict__ tmp, const float* __restrict__ gamma,
        const float* __restrict__ beta, float* __restrict__ out) {
    int m = blockIdx.x, t = threadIdx.x;
    int wv = t >> 6, lane = t & 63;
    float2 xv = *reinterpret_cast<const float2*>(&tmp[m * 512 + t * 2]);
    __shared__ float red[4];
    float s = xv.x + xv.y;
#pragma unroll
    for (int k = 32; k >= 1; k >>= 1) s += __shfl_xor(s, k, 64);
    if (lane == 0) red[wv] = s;
    __syncthreads();
    float mu = (red[0] + red[1] + red[2] + red[3]) * (1.0f / 512.0f);
    __syncthreads();
    float dx = xv.x - mu, dy = xv.y - mu;
    float vs = dx * dx + dy * dy;
#pragma unroll
    for (int k = 32; k >= 1; k >>= 1) vs += __shfl_xor(vs, k, 64);
    if (lane == 0) red[wv] = vs;
    __syncthreads();
    float var = (red[0] + red[1] + red[2] + red[3]) * (1.0f / 512.0f);
    float rstd = rsqrtf(var + 1e-12f);
    float2 g = *reinterpret_cast<const float2*>(&gamma[t * 2]);
    float2 be = *reinterpret_cast<const float2*>(&beta[t * 2]);
    float2 o;
    o.x = dx * rstd * g.x + be.x;
    o.y = dy * rstd * g.y + be.y;
    *reinterpret_cast<float2*>(&out[m * 512 + t * 2]) = o;
}

extern "C" void kernel_launch(void* const* d_in, const int* in_sizes, int n_in,
                              void* d_out, int out_size, void* d_ws, size_t ws_size,
                              hipStream_t stream) {
    const float* x     = (const float*)d_in[0];
    const float* pos   = (const float*)d_in[1];
    const int*   smask = (const int*)d_in[2];
    const float* Wq = (const float*)d_in[3];
    const float* bq = (const float*)d_in[4];
    const float* Wk = (const float*)d_in[5];
    const float* bk = (const float*)d_in[6];
    const float* Wv = (const float*)d_in[7];
    const float* bv = (const float*)d_in[8];
    const float* Wr = (const float*)d_in[9];
    const float* br = (const float*)d_in[10];
    const float* u  = (const float*)d_in[11];
    const float* vb = (const float*)d_in[12];
    const float* Wf = (const float*)d_in[13];
    const float* bf = (const float*)d_in[14];
    const float* gamma = (const float*)d_in[15];
    const float* beta  = (const float*)d_in[16];
    float* out = (float*)d_out;

    float* ws = (float*)d_ws;
    float* q_ws   = ws;                       // 262144 f
    float* k_ws   = q_ws  + 262144;           // 262144 f
    float* v_ws   = k_ws  + 262144;           // 262144 f
    float* w_ws   = v_ws  + 262144;           // 2097152 f
    float* c_ws   = w_ws  + 2097152;          // 4096 f
    float* uk_ws  = c_ws  + 4096;             // 4096 f
    float* vwr_ws = uk_ws + 4096;             // 4096 f
    float* ac_ws  = vwr_ws + 4096;            // 1048576 f
    float* ctx_ws = ac_ws + 1048576;          // 262144 f
    float* tmp_ws = ctx_ws + 262144;          // 262144 f
    float* wrt_ws = tmp_ws + 262144;          // 262144 f

    k_wrt<<<dim3(16, 16), 256, 0, stream>>>(Wr, wrt_ws);
    k_qkv<<<dim3(8, 8, 3), 256, 0, stream>>>(x, Wq, Wk, Wv, bq, bk, bv, q_ws, k_ws, v_ws);
    k_small<<<dim3(48), 256, 0, stream>>>(q_ws, k_ws, wrt_ws, u, vb, br, c_ws, uk_ws, vwr_ws);
    k_w<<<dim3(8, 8, 8), 256, 0, stream>>>(q_ws, wrt_ws, vwr_ws, w_ws);
    k_ac<<<dim3(4, 4, 16), 256, 0, stream>>>(q_ws, k_ws, uk_ws, c_ws, ac_ws);
    k_attn<<<dim3(512), 512, 0, stream>>>(pos, w_ws, ac_ws, v_ws, smask, ctx_ws);
    k_ffn<<<dim3(8, 8), 256, 0, stream>>>(ctx_ws, Wf, bf, x, tmp_ws);
    k_ln<<<dim3(512), 256, 0, stream>>>(tmp_ws, gamma, beta, out);
}

// Round 6
// 110.669 us; speedup vs baseline: 1.8209x; 1.0599x over previous
//
#include <hip/hip_runtime.h>
#include <cmath>

typedef __bf16 bf16x8 __attribute__((ext_vector_type(8)));
typedef float f32x4 __attribute__((ext_vector_type(4)));

__device__ __forceinline__ float4 ld4(const float* p) { return *reinterpret_cast<const float4*>(p); }
__device__ __forceinline__ void st4(float* p, float4 v) { *reinterpret_cast<float4*>(p) = v; }
__device__ __forceinline__ void fma4(float4& a, float s, const float4& v) {
    a.x = fmaf(s, v.x, a.x); a.y = fmaf(s, v.y, a.y);
    a.z = fmaf(s, v.z, a.z); a.w = fmaf(s, v.w, a.w);
}
__device__ __forceinline__ float dot4(const float4& a, const float4& b) {
    return a.x*b.x + a.y*b.y + a.z*b.z + a.w*b.w;
}
__device__ __forceinline__ unsigned short f2bf(float f) {
    unsigned int x = __float_as_uint(f);
    unsigned int r = x + 0x7FFFu + ((x >> 16) & 1u);
    return (unsigned short)(r >> 16);
}
__device__ __forceinline__ ushort4 cvt4u(float4 a) {
    ushort4 u;
    u.x = f2bf(a.x); u.y = f2bf(a.y); u.z = f2bf(a.z); u.w = f2bf(a.w);
    return u;
}
__device__ __forceinline__ bf16x8 cvt8(float4 a, float4 b) {
    bf16x8 r;
    r[0] = (__bf16)a.x; r[1] = (__bf16)a.y; r[2] = (__bf16)a.z; r[3] = (__bf16)a.w;
    r[4] = (__bf16)b.x; r[5] = (__bf16)b.y; r[6] = (__bf16)b.z; r[7] = (__bf16)b.w;
    return r;
}

// Core 64x64 MFMA tile: 4 waves, wave wv owns rows [wv*16, wv*16+16) x 64 cols.
__device__ __forceinline__ void mfma_tile(
        const float* __restrict__ Abase, int ldA,
        const float* __restrict__ Bbase, int ldB,
        int K, int lane, f32x4 acc[4]) {
    int koff = (lane >> 4) * 8;
    int rr = lane & 15;
    const float* ap = Abase + rr * ldA + koff;
    const float* bp = Bbase + rr * ldB + koff;
#pragma unroll 2
    for (int k0 = 0; k0 < K; k0 += 32) {
        float4 a0  = ld4(ap + k0),            a1  = ld4(ap + k0 + 4);
        float4 b00 = ld4(bp + k0),            b01 = ld4(bp + k0 + 4);
        float4 b10 = ld4(bp + 16*ldB + k0),   b11 = ld4(bp + 16*ldB + k0 + 4);
        float4 b20 = ld4(bp + 32*ldB + k0),   b21 = ld4(bp + 32*ldB + k0 + 4);
        float4 b30 = ld4(bp + 48*ldB + k0),   b31 = ld4(bp + 48*ldB + k0 + 4);
        bf16x8 af = cvt8(a0, a1);
        acc[0] = __builtin_amdgcn_mfma_f32_16x16x32_bf16(af, cvt8(b00, b01), acc[0], 0, 0, 0);
        acc[1] = __builtin_amdgcn_mfma_f32_16x16x32_bf16(af, cvt8(b10, b11), acc[1], 0, 0, 0);
        acc[2] = __builtin_amdgcn_mfma_f32_16x16x32_bf16(af, cvt8(b20, b21), acc[2], 0, 0, 0);
        acc[3] = __builtin_amdgcn_mfma_f32_16x16x32_bf16(af, cvt8(b30, b31), acc[3], 0, 0, 0);
    }
}

// ---------------- K1: q/k/v projections (192 blocks) + Wr transpose (64 blocks) ----------------
__global__ __launch_bounds__(256) void k_front(
        const float* __restrict__ x,
        const float* __restrict__ Wq, const float* __restrict__ Wk, const float* __restrict__ Wv,
        const float* __restrict__ bq, const float* __restrict__ bk, const float* __restrict__ bv,
        const float* __restrict__ Wr,
        float* __restrict__ qw, float* __restrict__ kw, float* __restrict__ vw,
        float* __restrict__ wrt) {
    int id = blockIdx.x;
    int t = threadIdx.x;
    if (id < 192) {
        int mat = id >> 6, rem = id & 63;
        int m0 = (rem >> 3) * 64, n0 = (rem & 7) * 64;
        const float* W   = (mat == 0) ? Wq : (mat == 1) ? Wk : Wv;
        const float* bias= (mat == 0) ? bq : (mat == 1) ? bk : bv;
        float* out       = (mat == 0) ? qw : (mat == 1) ? kw : vw;
        int wv = t >> 6, lane = t & 63;
        f32x4 acc[4] = {{0,0,0,0},{0,0,0,0},{0,0,0,0},{0,0,0,0}};
        mfma_tile(x + (m0 + wv * 16) * 512, 512, W + n0 * 512, 512, 512, lane, acc);
        int h = n0 >> 6;
        int col = lane & 15, rbase = (lane >> 4) * 4;
#pragma unroll
        for (int c = 0; c < 4; c++) {
            int d = c * 16 + col;
            float bv_ = bias[n0 + d];
#pragma unroll
            for (int r = 0; r < 4; r++) {
                int m = m0 + wv * 16 + rbase + r;
                int b = m >> 8, i = m & 255;
                out[((b * 8 + h) * 256 + i) * 64 + d] = acc[c][r] + bv_;
            }
        }
    } else {
        // transpose Wr[n][k] -> wrt[k][n], 64x64 tile
        __shared__ float tile[64][65];
        int id2 = id - 192;
        int n0 = (id2 >> 3) * 64, k0 = (id2 & 7) * 64;
        int tx = t & 63, ty = t >> 6;   // ty 0..3
#pragma unroll
        for (int r = 0; r < 16; r++) {
            int row = ty * 16 + r;
            tile[row][tx] = Wr[(n0 + row) * 512 + k0 + tx];
        }
        __syncthreads();
#pragma unroll
        for (int r = 0; r < 16; r++) {
            int row = ty * 16 + r;
            wrt[(k0 + row) * 512 + n0 + tx] = tile[tx][row];
        }
    }
}

// ---------------- K2: w-GEMM (512 blocks) + ac-GEMM (256 blocks), rank-1 terms inline ----------------
__global__ __launch_bounds__(256) void k_mid(
        const float* __restrict__ qw, const float* __restrict__ kw,
        const float* __restrict__ wrt,
        const float* __restrict__ u, const float* __restrict__ vb, const float* __restrict__ br,
        float* __restrict__ w_ws, float* __restrict__ ac_ws) {
    int id = blockIdx.x;
    int t = threadIdx.x, wv = t >> 6, lane = t & 63;
    __shared__ float red[8][64];   // partial-reduction scratch
    if (id < 512) {
        // w[b,i,h,e] = q_i . wrt[e, h*64:] + vwr[h,e]
        int h = id >> 6, rem = id & 63;
        int m0 = (rem >> 3) * 64, n0 = (rem & 7) * 64;
        int b = m0 >> 8, i0 = m0 & 255;
        // vwr partials: thread (e = t&63, grp = t>>6) covers d in [16grp,16grp+16)
        {
            int e = t & 63, grp = t >> 6;
            const float* wr_row = wrt + (size_t)(n0 + e) * 512 + h * 64 + grp * 16;
            const float* vbh = vb + h * 64 + grp * 16;
            float s = 0.f;
#pragma unroll
            for (int d = 0; d < 16; d += 4) s += dot4(ld4(wr_row + d), ld4(vbh + d));
            red[grp][e] = s;
        }
        __syncthreads();
        __shared__ float vwr_l[64];
        if (t < 64) vwr_l[t] = red[0][t] + red[1][t] + red[2][t] + red[3][t];
        f32x4 acc[4] = {{0,0,0,0},{0,0,0,0},{0,0,0,0},{0,0,0,0}};
        mfma_tile(qw + ((b * 8 + h) * 256 + i0 + wv * 16) * 64, 64,
                  wrt + (size_t)n0 * 512 + h * 64, 512, 64, lane, acc);
        __syncthreads();
        int col = lane & 15, rbase = (lane >> 4) * 4;
#pragma unroll
        for (int c = 0; c < 4; c++) {
            float vw_ = vwr_l[c * 16 + col];
            int n = n0 + c * 16 + col;
#pragma unroll
            for (int r = 0; r < 4; r++) {
                int m = m0 + wv * 16 + rbase + r;
                w_ws[((size_t)m * 8 + h) * 512 + n] = acc[c][r] + vw_;
            }
        }
    } else {
        // ac[b,i,h,j] = q_i.k_j + uk[j] + c[i]
        int id2 = id - 512;
        int bh = id2 >> 4, rem2 = id2 & 15;
        int b = bh >> 3, h = bh & 7;
        int i0 = (rem2 >> 2) * 64, j0 = (rem2 & 3) * 64;
        // c partials (i-range) and uk partials (j-range)
        {
            int xx = t & 63, grp = t >> 6;
            const float* qrow = qw + ((b * 8 + h) * 256 + i0 + xx) * 64 + grp * 16;
            const float* brh = br + h * 64 + grp * 16;
            const float* vbh = vb + h * 64 + grp * 16;
            float s = 0.f;
#pragma unroll
            for (int d = 0; d < 16; d += 4) {
                float4 q4 = ld4(qrow + d), b4 = ld4(brh + d), v4 = ld4(vbh + d);
                s += (q4.x + v4.x) * b4.x + (q4.y + v4.y) * b4.y
                   + (q4.z + v4.z) * b4.z + (q4.w + v4.w) * b4.w;
            }
            red[grp][xx] = s;
            const float* krow = kw + ((b * 8 + h) * 256 + j0 + xx) * 64 + grp * 16;
            const float* uh = u + h * 64 + grp * 16;
            s = 0.f;
#pragma unroll
            for (int d = 0; d < 16; d += 4) s += dot4(ld4(krow + d), ld4(uh + d));
            red[4 + grp][xx] = s;
        }
        __syncthreads();
        __shared__ float c_l[64], uk_l[64];
        if (t < 64) c_l[t] = red[0][t] + red[1][t] + red[2][t] + red[3][t];
        else if (t < 128) { int y = t - 64; uk_l[y] = red[4][y] + red[5][y] + red[6][y] + red[7][y]; }
        f32x4 acc[4] = {{0,0,0,0},{0,0,0,0},{0,0,0,0},{0,0,0,0}};
        mfma_tile(qw + ((b * 8 + h) * 256 + i0 + wv * 16) * 64, 64,
                  kw + ((b * 8 + h) * 256 + j0) * 64, 64, 64, lane, acc);
        __syncthreads();
        int col = lane & 15, rbase = (lane >> 4) * 4;
#pragma unroll
        for (int c = 0; c < 4; c++) {
            int j = j0 + c * 16 + col;
            float ukv = uk_l[c * 16 + col];
#pragma unroll
            for (int r = 0; r < 4; r++) {
                int ii = wv * 16 + rbase + r;
                ac_ws[((b * 256 + i0 + ii) * 8 + h) * 256 + j] = acc[c][r] + ukv + c_l[ii];
            }
        }
    }
}

// ---------------- K3: fused B_D (LDS-staged MFMA) + softmax + PV ----------------
// grid 512 = (b,i), block 512 = 8 waves; wave wv owns j-rows [32wv, 32wv+32)
__global__ __launch_bounds__(512, 4) void k_attn(
        const float* __restrict__ pos, const float* __restrict__ w_ws,
        const float* __restrict__ ac_ws, const float* __restrict__ vw,
        const int* __restrict__ seq_mask, float* __restrict__ ctx) {
    int bi = blockIdx.x;
    int b = bi >> 8, i = bi & 255;
    int t = threadIdx.x;
    int wv = t >> 6, lane = t & 63;
    __shared__ unsigned short wl[8 * 512];       // 8 KB  w B-frags (bf16)
    __shared__ float sc[8][256];                 // 8 KB  scores -> attn
    __shared__ unsigned short stage[8][4096];    // 64 KB wave-private staging; PV partials overlay

    // stage w (f32 -> bf16) into wl
    {
        int h = t >> 6;
        int e0 = (t & 63) * 8;
        const float* src = w_ws + ((size_t)bi * 8 + h) * 512 + e0;
        float4 a = ld4(src);
        float4 c = ld4(src + 4);
        *reinterpret_cast<ushort4*>(&wl[h * 512 + e0])     = cvt4u(a);
        *reinterpret_cast<ushort4*>(&wl[h * 512 + e0 + 4]) = cvt4u(c);
    }
    __syncthreads();

    const float* pb = pos + (size_t)bi * (256 * 512);
    int jbase = wv * 32;
    unsigned short* sb = &stage[wv][0];
    int arow = lane & 15;
    int koff = (lane >> 4) * 8;

#pragma unroll
    for (int jt = 0; jt < 2; jt++) {
        f32x4 acc = {0, 0, 0, 0};
#pragma unroll
        for (int eh = 0; eh < 2; eh++) {
            const float* src = pb + (size_t)(jbase + jt * 16) * 512 + eh * 256 + lane * 4;
            float4 tmp[16];
#pragma unroll
            for (int s = 0; s < 16; s++) tmp[s] = ld4(src + s * 512);
#pragma unroll
            for (int s = 0; s < 16; s++) {
                *reinterpret_cast<ushort4*>(&sb[s * 256 + lane * 4]) = cvt4u(tmp[s]);
            }
#pragma unroll
            for (int es = 0; es < 8; es++) {
                bf16x8 af = *reinterpret_cast<const bf16x8*>(&sb[arow * 256 + es * 32 + koff]);
                bf16x8 bf = *reinterpret_cast<const bf16x8*>(&wl[(lane & 7) * 512 + (eh * 8 + es) * 32 + koff]);
                acc = __builtin_amdgcn_mfma_f32_16x16x32_bf16(af, bf, acc, 0, 0, 0);
            }
        }
        int h = lane & 15;
        int rbase = (lane >> 4) * 4;
        if (h < 8) {
#pragma unroll
            for (int r = 0; r < 4; r++) sc[h][jbase + jt * 16 + rbase + r] = acc[r];
        }
    }
    __syncthreads();

    // softmax: wave wv owns head h = wv
    {
        int h = wv;
        const float* acrow = ac_ws + ((b * 256 + i) * 8 + h) * 256;
        float vals[4];
        float mx = -INFINITY;
#pragma unroll
        for (int r = 0; r < 4; r++) {
            int j = lane + r * 64;
            float s = (sc[h][j] + acrow[j]) * 0.125f;
            if (seq_mask[b * 256 + j] == 0) s = -1e15f;
            vals[r] = s;
            mx = fmaxf(mx, s);
        }
#pragma unroll
        for (int m = 32; m >= 1; m >>= 1) mx = fmaxf(mx, __shfl_xor(mx, m, 64));
        float sum = 0.f;
#pragma unroll
        for (int r = 0; r < 4; r++) { vals[r] = __expf(vals[r] - mx); sum += vals[r]; }
#pragma unroll
        for (int m = 32; m >= 1; m >>= 1) sum += __shfl_xor(sum, m, 64);
        float inv = 1.0f / sum;
#pragma unroll
        for (int r = 0; r < 4; r++) sc[h][lane + r * 64] = vals[r] * inv;
    }
    // no barrier needed: PV uses wave-private data

    // PV: wave = head; lane -> (jsplit = lane>>4, d4 = (lane&15)*4); unrolled for MLP
    float4* part = reinterpret_cast<float4*>(&stage[0][0]);  // [8][4][16] float4 overlay
    {
        int h = wv;
        int d4 = (lane & 15) * 4;
        int js = lane >> 4;
        const float* vbase = vw + (size_t)(b * 8 + h) * 256 * 64 + d4;
        float4 acc = {0, 0, 0, 0};
#pragma unroll 2
        for (int r = 0; r < 64; r += 4) {
            int j = js * 64 + r;
            float p0 = sc[h][j + 0], p1 = sc[h][j + 1];
            float p2 = sc[h][j + 2], p3 = sc[h][j + 3];
            float4 v0 = ld4(vbase + (size_t)(j + 0) * 64);
            float4 v1 = ld4(vbase + (size_t)(j + 1) * 64);
            float4 v2 = ld4(vbase + (size_t)(j + 2) * 64);
            float4 v3 = ld4(vbase + (size_t)(j + 3) * 64);
            fma4(acc, p0, v0); fma4(acc, p1, v1);
            fma4(acc, p2, v2); fma4(acc, p3, v3);
        }
        part[(h * 4 + js) * 16 + (lane & 15)] = acc;
    }
    {
        int h = wv;
        if ((lane >> 4) == 0) {
            int l = lane & 15;
            float4 a0 = part[(h * 4 + 0) * 16 + l], a1 = part[(h * 4 + 1) * 16 + l];
            float4 a2 = part[(h * 4 + 2) * 16 + l], a3 = part[(h * 4 + 3) * 16 + l];
            float4 o;
            o.x = a0.x + a1.x + a2.x + a3.x;
            o.y = a0.y + a1.y + a2.y + a3.y;
            o.z = a0.z + a1.z + a2.z + a3.z;
            o.w = a0.w + a1.w + a2.w + a3.w;
            st4(ctx + (size_t)(b * 256 + i) * 512 + h * 64 + l * 4, o);
        }
    }
}

// ---------------- K4: FFN GEMM + bias + residual (MFMA) ----------------
__global__ __launch_bounds__(256) void k_ffn(
        const float* __restrict__ A, const float* __restrict__ Wf,
        const float* __restrict__ bias, const float* __restrict__ resid,
        float* __restrict__ outp) {
    int m0 = blockIdx.x * 64, n0 = blockIdx.y * 64;
    int t = threadIdx.x, wv = t >> 6, lane = t & 63;
    f32x4 acc[4] = {{0,0,0,0},{0,0,0,0},{0,0,0,0},{0,0,0,0}};
    mfma_tile(A + (m0 + wv * 16) * 512, 512, Wf + n0 * 512, 512, 512, lane, acc);
    int col = lane & 15, rbase = (lane >> 4) * 4;
#pragma unroll
    for (int c = 0; c < 4; c++) {
        int n = n0 + c * 16 + col;
        float bv_ = bias[n];
#pragma unroll
        for (int r = 0; r < 4; r++) {
            int m = m0 + wv * 16 + rbase + r;
            outp[m * 512 + n] = acc[c][r] + bv_ + resid[m * 512 + n];
        }
    }
}

// ---------------- K5: LayerNorm ----------------
__global__ __launch_bounds__(256) void k_ln(
        const float* __restrict__ tmp, const float* __restrict__ gamma,
        const float* __restrict__ beta, float* __restrict__ out) {
    int m = blockIdx.x, t = threadIdx.x;
    int wv = t >> 6, lane = t & 63;
    float2 xv = *reinterpret_cast<const float2*>(&tmp[m * 512 + t * 2]);
    __shared__ float red[4];
    float s = xv.x + xv.y;
#pragma unroll
    for (int k = 32; k >= 1; k >>= 1) s += __shfl_xor(s, k, 64);
    if (lane == 0) red[wv] = s;
    __syncthreads();
    float mu = (red[0] + red[1] + red[2] + red[3]) * (1.0f / 512.0f);
    __syncthreads();
    float dx = xv.x - mu, dy = xv.y - mu;
    float vs = dx * dx + dy * dy;
#pragma unroll
    for (int k = 32; k >= 1; k >>= 1) vs += __shfl_xor(vs, k, 64);
    if (lane == 0) red[wv] = vs;
    __syncthreads();
    float var = (red[0] + red[1] + red[2] + red[3]) * (1.0f / 512.0f);
    float rstd = rsqrtf(var + 1e-12f);
    float2 g = *reinterpret_cast<const float2*>(&gamma[t * 2]);
    float2 be = *reinterpret_cast<const float2*>(&beta[t * 2]);
    float2 o;
    o.x = dx * rstd * g.x + be.x;
    o.y = dy * rstd * g.y + be.y;
    *reinterpret_cast<float2*>(&out[m * 512 + t * 2]) = o;
}

extern "C" void kernel_launch(void* const* d_in, const int* in_sizes, int n_in,
                              void* d_out, int out_size, void* d_ws, size_t ws_size,
                              hipStream_t stream) {
    const float* x     = (const float*)d_in[0];
    const float* pos   = (const float*)d_in[1];
    const int*   smask = (const int*)d_in[2];
    const float* Wq = (const float*)d_in[3];
    const float* bq = (const float*)d_in[4];
    const float* Wk = (const float*)d_in[5];
    const float* bk = (const float*)d_in[6];
    const float* Wv = (const float*)d_in[7];
    const float* bv = (const float*)d_in[8];
    const float* Wr = (const float*)d_in[9];
    const float* br = (const float*)d_in[10];
    const float* u  = (const float*)d_in[11];
    const float* vb = (const float*)d_in[12];
    const float* Wf = (const float*)d_in[13];
    const float* bf = (const float*)d_in[14];
    const float* gamma = (const float*)d_in[15];
    const float* beta  = (const float*)d_in[16];
    float* out = (float*)d_out;

    float* ws = (float*)d_ws;
    float* q_ws   = ws;                       // 262144 f
    float* k_ws   = q_ws  + 262144;           // 262144 f
    float* v_ws   = k_ws  + 262144;           // 262144 f
    float* w_ws   = v_ws  + 262144;           // 2097152 f
    float* ac_ws  = w_ws  + 2097152;          // 1048576 f
    float* ctx_ws = ac_ws + 1048576;          // 262144 f
    float* tmp_ws = ctx_ws + 262144;          // 262144 f
    float* wrt_ws = tmp_ws + 262144;          // 262144 f

    k_front<<<dim3(256), 256, 0, stream>>>(x, Wq, Wk, Wv, bq, bk, bv, Wr,
                                           q_ws, k_ws, v_ws, wrt_ws);
    k_mid<<<dim3(768), 256, 0, stream>>>(q_ws, k_ws, wrt_ws, u, vb, br, w_ws, ac_ws);
    k_attn<<<dim3(512), 512, 0, stream>>>(pos, w_ws, ac_ws, v_ws, smask, ctx_ws);
    k_ffn<<<dim3(8, 8), 256, 0, stream>>>(ctx_ws, Wf, bf, x, tmp_ws);
    k_ln<<<dim3(512), 256, 0, stream>>>(tmp_ws, gamma, beta, out);
}